// Round 2
// baseline (1234.651 us; speedup 1.0000x reference)
//
#include <hip/hip_runtime.h>
#include <cstdint>

// ---------------------------------------------------------------------------
// PerceiverResampler on MI355X (gfx950) — round 2: m97-class GEMM
// (128x128 tile, global_load_lds w16, 2-barrier K-loop) + fused Wkv fold.
// B=32 SEQ=512 DIM=1024 DEPTH=6 HEADS=8 DHEAD=64 INNER=512 NLAT=64
// ---------------------------------------------------------------------------

#define DEVINL __device__ __forceinline__

typedef __attribute__((ext_vector_type(8))) short short8_t;   // 8 x bf16 (4 VGPR)
typedef __attribute__((ext_vector_type(4))) float f32x4;      // MFMA acc

DEVINL ushort f2bf(float f) {          // RNE f32 -> bf16 (finite inputs)
  union { float f; uint32_t u; } c; c.f = f;
  uint32_t u = c.u;
  u += ((u >> 16) & 1u) + 0x7fffu;
  return (ushort)(u >> 16);
}
DEVINL float bf2f(ushort u) {
  union { uint32_t u; float f; } c; c.u = ((uint32_t)u) << 16;
  return c.f;
}
DEVINL f32x4 mfma16(short8_t a, short8_t b, f32x4 c) {
  // D: col = lane&15, row = (lane>>4)*4 + r   [guide-verified C/D layout]
  return __builtin_amdgcn_mfma_f32_16x16x32_bf16(a, b, c, 0, 0, 0);
}
// async global->LDS, 16B per lane. lds base must be wave-uniform; HW writes
// lane i at base + i*16. global src is per-lane.
DEVINL void gld16(ushort* lds, const ushort* g) {
  __builtin_amdgcn_global_load_lds(
      (const __attribute__((address_space(1))) void*)g,
      (__attribute__((address_space(3))) void*)lds, 16, 0, 0);
}

// ---------------------------------------------------------------------------
// Fused Wkv fold: read Wkv[l] once, write both folded transposes.
// wkvmT[l][c][r] = bf16(W[l][r][c]*lnmg[l][r]);  wkvlT likewise with lnlg.
// grid (32, 32, 6), block 256
__global__ __launch_bounds__(256) void k_fold_kv(const float* __restrict__ Wkv,
    const float* __restrict__ lnmg, const float* __restrict__ lnlg,
    ushort* __restrict__ wkvmT, ushort* __restrict__ wkvlT) {
  __shared__ float tile[32][33];
  int l = blockIdx.z;
  const float* Wl = Wkv + (size_t)l * 1048576;
  int r0 = blockIdx.y * 32, c0 = blockIdx.x * 32;
  int tx = threadIdx.x & 31, ty = threadIdx.x >> 5;
#pragma unroll
  for (int i = 0; i < 4; ++i)
    tile[ty + i * 8][tx] = Wl[(size_t)(r0 + ty + i * 8) * 1024 + c0 + tx];
  __syncthreads();
#pragma unroll
  for (int i = 0; i < 4; ++i) {
    int jl = ty + i * 8;                   // col within tile
    float wv = tile[tx][jl];               // W[r0+tx][c0+jl]
    int r = r0 + tx, c = c0 + jl;
    size_t o = (size_t)l * 1048576 + (size_t)c * 1024 + r;
    wkvmT[o] = f2bf(wv * lnmg[l * 1024 + r]);
    wkvlT[o] = f2bf(wv * lnlg[l * 1024 + r]);
  }
}

// Fold + transpose (Wq, Wout): outT[l][c][r] = bf16(W[l][r][c]*g[l][r]*scale)
__global__ __launch_bounds__(256) void k_fold_T(const float* __restrict__ W,
    const float* __restrict__ g, float scale, ushort* __restrict__ outT,
    int R, int C) {
  __shared__ float tile[32][33];
  int l = blockIdx.z;
  const float* Wl = W + (size_t)l * R * C;
  const float* gl = g ? g + (size_t)l * R : nullptr;
  ushort* Ol = outT + (size_t)l * R * C;
  int r0 = blockIdx.y * 32, c0 = blockIdx.x * 32;
  int tx = threadIdx.x & 31, ty = threadIdx.x >> 5;
#pragma unroll
  for (int i = 0; i < 4; ++i) {
    int r = ty + i * 8;
    float gv = gl ? gl[r0 + r] : 1.0f;
    tile[r][tx] = Wl[(size_t)(r0 + r) * C + c0 + tx] * gv * scale;
  }
  __syncthreads();
#pragma unroll
  for (int i = 0; i < 4; ++i) {
    int jl = ty + i * 8;
    Ol[(size_t)(c0 + jl) * R + r0 + tx] = f2bf(tile[tx][jl]);
  }
}

// ---------------------------------------------------------------------------
// Bias rows (see round 1). grid (40, 6), block 256.
__global__ __launch_bounds__(256) void k_bias_rows(const float* __restrict__ Wkv,
    const float* __restrict__ Wq, const float* __restrict__ lnmb,
    const float* __restrict__ lnlb, float* __restrict__ bkvm,
    float* __restrict__ bkvl, float* __restrict__ bq) {
  __shared__ float red[4][64];
  int l = blockIdx.y;
  int c0 = blockIdx.x * 64;
  int tx = threadIdx.x & 63, dg = threadIdx.x >> 6;
  const float* Wsrc; const float* bv; int ld; float scale = 1.0f; float* outp;
  if (c0 < 1024) {
    Wsrc = Wkv + (size_t)l * 1048576 + c0 + tx; bv = lnmb + l * 1024; ld = 1024;
    outp = bkvm + l * 1024 + c0 + tx;
  } else if (c0 < 2048) {
    Wsrc = Wkv + (size_t)l * 1048576 + (c0 - 1024) + tx; bv = lnlb + l * 1024; ld = 1024;
    outp = bkvl + l * 1024 + (c0 - 1024) + tx;
  } else {
    Wsrc = Wq + (size_t)l * 524288 + (c0 - 2048) + tx; bv = lnlb + l * 1024; ld = 512;
    outp = bq + l * 512 + (c0 - 2048) + tx; scale = 0.125f;
  }
  float acc = 0.f;
  for (int d = dg * 256; d < dg * 256 + 256; ++d)
    acc += bv[d] * Wsrc[(size_t)d * ld];
  red[dg][tx] = acc;
  __syncthreads();
  if (dg == 0) *outp = (red[0][tx] + red[1][tx] + red[2][tx] + red[3][tx]) * scale;
}

// ---------------------------------------------------------------------------
// Row layernorm (no affine) -> bf16. Optional pos add (row&511).
__global__ __launch_bounds__(256) void k_rownorm(const float* __restrict__ in,
    const float* __restrict__ pos, ushort* __restrict__ out) {
  int row = blockIdx.x, t = threadIdx.x;
  float4 v = *(const float4*)(in + (size_t)row * 1024 + t * 4);
  if (pos) {
    float4 p = *(const float4*)(pos + (size_t)(row & 511) * 1024 + t * 4);
    v.x += p.x; v.y += p.y; v.z += p.z; v.w += p.w;
  }
  float s = v.x + v.y + v.z + v.w;
  float q = v.x * v.x + v.y * v.y + v.z * v.z + v.w * v.w;
#pragma unroll
  for (int off = 32; off; off >>= 1) { s += __shfl_xor(s, off); q += __shfl_xor(q, off); }
  __shared__ float rs[4], rq[4];
  if ((t & 63) == 0) { rs[t >> 6] = s; rq[t >> 6] = q; }
  __syncthreads();
  s = rs[0] + rs[1] + rs[2] + rs[3];
  q = rq[0] + rq[1] + rq[2] + rq[3];
  float mean = s * (1.0f / 1024.0f);
  float var = q * (1.0f / 1024.0f) - mean * mean;
  float rstd = rsqrtf(var + 1e-5f);
  ushort4 o;
  o.x = f2bf((v.x - mean) * rstd);
  o.y = f2bf((v.y - mean) * rstd);
  o.z = f2bf((v.z - mean) * rstd);
  o.w = f2bf((v.w - mean) * rstd);
  *(ushort4*)(out + (size_t)row * 1024 + t * 4) = o;
}

// Final layernorm with affine -> f32 out.
__global__ __launch_bounds__(256) void k_finalln(const float* __restrict__ in,
    const float* __restrict__ g, const float* __restrict__ b, float* __restrict__ out) {
  int row = blockIdx.x, t = threadIdx.x;
  float4 v = *(const float4*)(in + (size_t)row * 1024 + t * 4);
  float s = v.x + v.y + v.z + v.w;
  float q = v.x * v.x + v.y * v.y + v.z * v.z + v.w * v.w;
#pragma unroll
  for (int off = 32; off; off >>= 1) { s += __shfl_xor(s, off); q += __shfl_xor(q, off); }
  __shared__ float rs[4], rq[4];
  if ((t & 63) == 0) { rs[t >> 6] = s; rq[t >> 6] = q; }
  __syncthreads();
  s = rs[0] + rs[1] + rs[2] + rs[3];
  q = rq[0] + rq[1] + rq[2] + rq[3];
  float mean = s * (1.0f / 1024.0f);
  float var = q * (1.0f / 1024.0f) - mean * mean;
  float rstd = rsqrtf(var + 1e-5f);
  float4 g4 = *(const float4*)(g + t * 4);
  float4 b4 = *(const float4*)(b + t * 4);
  float4 o;
  o.x = (v.x - mean) * rstd * g4.x + b4.x;
  o.y = (v.y - mean) * rstd * g4.y + b4.y;
  o.z = (v.z - mean) * rstd * g4.z + b4.z;
  o.w = (v.w - mean) * rstd * g4.w + b4.w;
  *(float4*)(out + (size_t)row * 1024 + t * 4) = o;
}

__global__ __launch_bounds__(256) void k_latinit(const float* __restrict__ latents,
                                                 float* __restrict__ lat) {
  int row = blockIdx.x, t = threadIdx.x;
  *(float4*)(lat + (size_t)row * 1024 + t * 4) =
      *(const float4*)(latents + (size_t)(row & 63) * 1024 + t * 4);
}

// ---------------------------------------------------------------------------
// m97-class GEMM: C[M,N] = A[M,K](bf16 rm) @ Bt[N,K]^T + bias[N]
// 128x128 tile, 4 waves (2x2 of 64x64), BK=32, global_load_lds w16,
// 2-barrier K-loop (compiler drains vmcnt/lgkmcnt at __syncthreads).
// MODE 0: bf16 outA[row*N+col]
// MODE 1: KV split: b=row>>rowshift, jr=jbase+(row&mask);
//         col<512 -> outA[((b*576+jr)<<9)+col] else outB[...+col-512]
// MODE 2: outF[row*N+col] += v (residual, f32)
template <int MODE>
__global__ __launch_bounds__(256) void k_gemm128(const ushort* __restrict__ A,
    const ushort* __restrict__ Bt, const float* __restrict__ bias,
    ushort* __restrict__ outA, ushort* __restrict__ outB, float* __restrict__ outF,
    int M, int N, int K, int rowshift, int jbase) {
  __shared__ ushort Al[128][32];   // linear — required by global_load_lds
  __shared__ ushort Bl[128][32];
  int tid = threadIdx.x;
  int lane = tid & 63, w = tid >> 6;
  int wr = w >> 1, wc = w & 1;
  int m0 = blockIdx.y * 128, n0 = blockIdx.x * 128;
  f32x4 acc[4][4] = {};
  // staging: wave w covers rows w*32..w*32+31 of each tile, 2 issues apiece.
  int srow = lane >> 2;            // 0..15
  int scol = (lane & 3) * 8;       // element offset (16B chunks)
  const ushort* Ag = A + (size_t)(m0 + w * 32 + srow) * K + scol;
  const ushort* Bg = Bt + (size_t)(n0 + w * 32 + srow) * K + scol;
  ushort* Al0 = &Al[w * 32][0];
  ushort* Al1 = &Al[w * 32 + 16][0];
  ushort* Bl0 = &Bl[w * 32][0];
  ushort* Bl1 = &Bl[w * 32 + 16][0];
  int fr = lane & 15, fk = (lane >> 4) << 3;
  for (int k0 = 0; k0 < K; k0 += 32) {
    __syncthreads();               // prev iter's LDS reads complete
    gld16(Al0, Ag + k0);
    gld16(Al1, Ag + k0 + (size_t)16 * K);
    gld16(Bl0, Bg + k0);
    gld16(Bl1, Bg + k0 + (size_t)16 * K);
    __syncthreads();               // drains vmcnt(0) -> tile ready
    short8_t a[4], b[4];
#pragma unroll
    for (int mt = 0; mt < 4; ++mt)
      a[mt] = *(const short8_t*)&Al[wr * 64 + mt * 16 + fr][fk];
#pragma unroll
    for (int nt = 0; nt < 4; ++nt)
      b[nt] = *(const short8_t*)&Bl[wc * 64 + nt * 16 + fr][fk];
#pragma unroll
    for (int mt = 0; mt < 4; ++mt)
#pragma unroll
      for (int nt = 0; nt < 4; ++nt)
        acc[mt][nt] = mfma16(a[mt], b[nt], acc[mt][nt]);
  }
#pragma unroll
  for (int mt = 0; mt < 4; ++mt)
#pragma unroll
    for (int nt = 0; nt < 4; ++nt)
#pragma unroll
      for (int r = 0; r < 4; ++r) {
        int row = m0 + wr * 64 + mt * 16 + ((lane >> 4) << 2) + r;
        int col = n0 + wc * 64 + nt * 16 + (lane & 15);
        float v = acc[mt][nt][r] + (bias ? bias[col] : 0.0f);
        if constexpr (MODE == 0) {
          outA[(size_t)row * N + col] = f2bf(v);
        } else if constexpr (MODE == 1) {
          int b_ = row >> rowshift;
          int jr = jbase + (row & ((1 << rowshift) - 1));
          size_t base = ((size_t)(b_ * 576 + jr)) << 9;
          if (col < 512) outA[base + col] = f2bf(v);
          else           outB[base + col - 512] = f2bf(v);
        } else {
          outF[(size_t)row * N + col] += v;
        }
      }
}

// ---------------------------------------------------------------------------
// Fused attention, one block per (b, h, half-of-32-rows). 256 thr = 4 waves.
__global__ __launch_bounds__(256) void k_attn(const ushort* __restrict__ Q,
    const ushort* __restrict__ Kb, const ushort* __restrict__ Vb,
    const int* __restrict__ amask, ushort* __restrict__ AO) {
  __shared__ ushort sim[32][584];
  __shared__ ushort kt[64][72];
  int blk = blockIdx.x;
  int half = blk & 1, h = (blk >> 1) & 7, b = blk >> 4;
  int tid = threadIdx.x, lane = tid & 63, w = tid >> 6;
  int wr = w >> 1, wc = w & 1;
  short8_t aq0, aq1;
  {
    int qi = half * 32 + wr * 16 + (lane & 15);
    const ushort* qp = Q + ((size_t)(b * 64 + qi) << 9) + h * 64 + ((lane >> 4) << 3);
    aq0 = *(const short8_t*)qp;
    aq1 = *(const short8_t*)(qp + 32);
  }
  int sr = tid >> 2, scol = (tid & 3) << 4;
  // ---- phase 1: S = Q @ K^T -> sim (bf16)
  for (int jt = 0; jt < 9; ++jt) {
    const ushort* kp = Kb + ((size_t)(b * 576 + jt * 64 + sr) << 9) + h * 64 + scol;
    short8_t k0 = *(const short8_t*)kp;
    short8_t k1 = *(const short8_t*)(kp + 8);
    __syncthreads();
    *(short8_t*)&kt[sr][scol] = k0;
    *(short8_t*)&kt[sr][scol + 8] = k1;
    __syncthreads();
#pragma unroll
    for (int c2 = 0; c2 < 2; ++c2) {
      int ct = wc * 2 + c2;
      f32x4 acc = {};
      short8_t bk0 = *(const short8_t*)&kt[ct * 16 + (lane & 15)][(lane >> 4) << 3];
      short8_t bk1 = *(const short8_t*)&kt[ct * 16 + (lane & 15)][32 + ((lane >> 4) << 3)];
      acc = mfma16(aq0, bk0, acc);
      acc = mfma16(aq1, bk1, acc);
#pragma unroll
      for (int r = 0; r < 4; ++r)
        sim[wr * 16 + ((lane >> 4) << 2) + r][jt * 64 + ct * 16 + (lane & 15)] =
            f2bf(acc[r]);
    }
  }
  __syncthreads();
  // ---- phase 2: masked softmax per row
  unsigned mbits = 0;
#pragma unroll
  for (int c = 1; c < 9; ++c)
    if (amask[b * 512 + (c - 1) * 64 + lane]) mbits |= (1u << c);
  for (int rr = 0; rr < 8; ++rr) {
    int row = w * 8 + rr;
    float vals[9];
    float m = -3.0e38f;
#pragma unroll
    for (int c = 0; c < 9; ++c) {
      float v = bf2f(sim[row][c * 64 + lane]);
      vals[c] = v;
      if (!((mbits >> c) & 1)) m = fmaxf(m, v);
    }
#pragma unroll
    for (int off = 32; off; off >>= 1) m = fmaxf(m, __shfl_xor(m, off));
    float ssum = 0.f;
    float p[9];
#pragma unroll
    for (int c = 0; c < 9; ++c) {
      p[c] = ((mbits >> c) & 1) ? 0.f : __expf(vals[c] - m);
      ssum += p[c];
    }
#pragma unroll
    for (int off = 32; off; off >>= 1) ssum += __shfl_xor(ssum, off);
    float inv = 1.0f / ssum;
#pragma unroll
    for (int c = 0; c < 9; ++c)
      sim[row][c * 64 + lane] = f2bf(p[c] * inv);
  }
  __syncthreads();
  // ---- phase 3: O = P @ V
  f32x4 oacc[2] = {};
  for (int jt = 0; jt < 9; ++jt) {
    const ushort* vp = Vb + ((size_t)(b * 576 + jt * 64 + sr) << 9) + h * 64 + scol;
    short8_t v0 = *(const short8_t*)vp;
    short8_t v1 = *(const short8_t*)(vp + 8);
    __syncthreads();
#pragma unroll
    for (int e = 0; e < 8; ++e) kt[scol + e][sr] = (ushort)v0[e];
#pragma unroll
    for (int e = 0; e < 8; ++e) kt[scol + 8 + e][sr] = (ushort)v1[e];
    __syncthreads();
#pragma unroll
    for (int d2 = 0; d2 < 2; ++d2) {
      int dt = wc * 2 + d2;
      short8_t pa0 = *(const short8_t*)&sim[wr * 16 + (lane & 15)][jt * 64 + ((lane >> 4) << 3)];
      short8_t pa1 = *(const short8_t*)&sim[wr * 16 + (lane & 15)][jt * 64 + 32 + ((lane >> 4) << 3)];
      short8_t bv0 = *(const short8_t*)&kt[dt * 16 + (lane & 15)][(lane >> 4) << 3];
      short8_t bv1 = *(const short8_t*)&kt[dt * 16 + (lane & 15)][32 + ((lane >> 4) << 3)];
      oacc[d2] = mfma16(pa0, bv0, oacc[d2]);
      oacc[d2] = mfma16(pa1, bv1, oacc[d2]);
    }
  }
#pragma unroll
  for (int d2 = 0; d2 < 2; ++d2) {
    int dt = wc * 2 + d2;
#pragma unroll
    for (int r = 0; r < 4; ++r) {
      int i = half * 32 + wr * 16 + ((lane >> 4) << 2) + r;
      int d = dt * 16 + (lane & 15);
      AO[((size_t)(b * 64 + i) << 9) + h * 64 + d] = f2bf(oacc[d2][r]);
    }
  }
}

// ---------------------------------------------------------------------------
extern "C" void kernel_launch(void* const* d_in, const int* in_sizes, int n_in,
                              void* d_out, int out_size, void* d_ws, size_t ws_size,
                              hipStream_t stream) {
  const float* x       = (const float*)d_in[0];
  const int*   amask   = (const int*)d_in[1];
  const float* latents = (const float*)d_in[2];
  const float* pos     = (const float*)d_in[3];
  const float* lnmg    = (const float*)d_in[4];
  const float* lnmb    = (const float*)d_in[5];
  const float* lnlg    = (const float*)d_in[6];
  const float* lnlb    = (const float*)d_in[7];
  const float* Wq      = (const float*)d_in[8];
  const float* Wkv     = (const float*)d_in[9];
  const float* Wout    = (const float*)d_in[10];
  const float* fg      = (const float*)d_in[11];
  const float* fb      = (const float*)d_in[12];
  float* out = (float*)d_out;
  char* ws = (char*)d_ws;

  ushort* xhat  = (ushort*)(ws + 0);           // [16384][1024] bf16   32 MiB
  ushort* wkvmT = (ushort*)(ws + 33554432);    // [6][1024][1024] bf16 12 MiB
  ushort* wkvlT = (ushort*)(ws + 46137344);    // [6][1024][1024] bf16 12 MiB
  ushort* wqT   = (ushort*)(ws + 58720256);    // [6][512][1024]  bf16  6 MiB
  ushort* woutT = (ushort*)(ws + 65011712);    // [6][1024][512]  bf16  6 MiB
  float*  bkvm  = (float*)(ws + 71303168);     // [6][1024] f32
  float*  bkvl  = (float*)(ws + 71327744);     // [6][1024] f32
  float*  bq    = (float*)(ws + 71352320);     // [6][512]  f32
  float*  lat   = (float*)(ws + 71364608);     // [2048][1024] f32      8 MiB
  ushort* lhat  = (ushort*)(ws + 79753216);    // [2048][1024] bf16     4 MiB
  ushort* qbuf  = (ushort*)(ws + 83947520);    // [2048][512]  bf16     2 MiB
  ushort* Kbuf  = (ushort*)(ws + 86044672);    // [32][576][512] bf16  18 MiB
  ushort* Vbuf  = (ushort*)(ws + 104919040);   // [32][576][512] bf16  18 MiB
  ushort* aobuf = (ushort*)(ws + 123793408);   // [2048][512]  bf16     2 MiB

  dim3 B256(256);
  k_fold_kv<<<dim3(32, 32, 6), B256, 0, stream>>>(Wkv, lnmg, lnlg, wkvmT, wkvlT);
  k_fold_T<<<dim3(16, 32, 6), B256, 0, stream>>>(Wq, lnlg, 0.125f, wqT, 1024, 512);
  k_fold_T<<<dim3(32, 16, 6), B256, 0, stream>>>(Wout, nullptr, 1.0f, woutT, 512, 1024);
  k_bias_rows<<<dim3(40, 6), B256, 0, stream>>>(Wkv, Wq, lnmb, lnlb, bkvm, bkvl, bq);
  k_rownorm<<<16384, B256, 0, stream>>>(x, pos, xhat);
  k_latinit<<<2048, B256, 0, stream>>>(latents, lat);

  for (int l = 0; l < 6; ++l) {
    k_rownorm<<<2048, B256, 0, stream>>>(lat, nullptr, lhat);
    // q = l̂at @ (0.125 g⊙Wq) + bq  -> bf16 [2048][512]
    k_gemm128<0><<<dim3(4, 16), B256, 0, stream>>>(
        lhat, wqT + (size_t)l * 524288, bq + l * 512, qbuf, nullptr, nullptr,
        2048, 512, 1024, 0, 0);
    // latent kv rows (j = 0..63)
    k_gemm128<1><<<dim3(8, 16), B256, 0, stream>>>(
        lhat, wkvlT + (size_t)l * 1048576, bkvl + l * 1024, Kbuf, Vbuf, nullptr,
        2048, 1024, 1024, 6, 0);
    // media kv rows (j = 64..575) — dominant GEMM, m97 structure
    k_gemm128<1><<<dim3(8, 128), B256, 0, stream>>>(
        xhat, wkvmT + (size_t)l * 1048576, bkvm + l * 1024, Kbuf, Vbuf, nullptr,
        16384, 1024, 1024, 9, 64);
    k_attn<<<512, B256, 0, stream>>>(qbuf, Kbuf, Vbuf, amask, aobuf);
    // lat += attn_out @ Wout
    k_gemm128<2><<<dim3(8, 16), B256, 0, stream>>>(
        aobuf, woutT + (size_t)l * 524288, nullptr, nullptr, nullptr, lat,
        2048, 1024, 512, 0, 0);
  }
  k_finalln<<<2048, B256, 0, stream>>>(lat, fg, fb, out);
}

// Round 3
// 767.396 us; speedup vs baseline: 1.6089x; 1.6089x over previous
//
#include <hip/hip_runtime.h>
#include <cstdint>

// ---------------------------------------------------------------------------
// PerceiverResampler on MI355X (gfx950) — round 3:
//  * 2-phase double-buffered GEMMs (stage-early: T3 minimum recipe)
//  * merged latent GEMM (q | k_lat | v_lat in one N=1536 dispatch)
//  * 64^2 tile for latent GEMMs (grid parallelism), 128^2 for media
// B=32 SEQ=512 DIM=1024 DEPTH=6 HEADS=8 DHEAD=64 INNER=512 NLAT=64
// ---------------------------------------------------------------------------

#define DEVINL __device__ __forceinline__

typedef __attribute__((ext_vector_type(8))) short short8_t;   // 8 x bf16
typedef __attribute__((ext_vector_type(4))) float f32x4;

DEVINL ushort f2bf(float f) {
  union { float f; uint32_t u; } c; c.f = f;
  uint32_t u = c.u;
  u += ((u >> 16) & 1u) + 0x7fffu;
  return (ushort)(u >> 16);
}
DEVINL float bf2f(ushort u) {
  union { uint32_t u; float f; } c; c.u = ((uint32_t)u) << 16;
  return c.f;
}
DEVINL f32x4 mfma16(short8_t a, short8_t b, f32x4 c) {
  return __builtin_amdgcn_mfma_f32_16x16x32_bf16(a, b, c, 0, 0, 0);
}
DEVINL void gld16(ushort* lds, const ushort* g) {
  __builtin_amdgcn_global_load_lds(
      (const __attribute__((address_space(1))) void*)g,
      (__attribute__((address_space(3))) void*)lds, 16, 0, 0);
}

// ---------------------------------------------------------------------------
// Fused Wkv fold: one read of Wkv[l]; write media-folded transpose (wkvmT)
// and latent-folded transpose into the combined latent weight (wlatT, +512).
// grid (32, 32, 6), block 256
__global__ __launch_bounds__(256) void k_fold_kv(const float* __restrict__ Wkv,
    const float* __restrict__ lnmg, const float* __restrict__ lnlg,
    ushort* __restrict__ wkvmT, ushort* __restrict__ wlatT) {
  __shared__ float tile[32][33];
  int l = blockIdx.z;
  const float* Wl = Wkv + (size_t)l * 1048576;
  int r0 = blockIdx.y * 32, c0 = blockIdx.x * 32;
  int tx = threadIdx.x & 31, ty = threadIdx.x >> 5;
#pragma unroll
  for (int i = 0; i < 4; ++i)
    tile[ty + i * 8][tx] = Wl[(size_t)(r0 + ty + i * 8) * 1024 + c0 + tx];
  __syncthreads();
#pragma unroll
  for (int i = 0; i < 4; ++i) {
    int jl = ty + i * 8;
    float wv = tile[tx][jl];             // W[r0+tx][c0+jl]
    int r = r0 + tx, c = c0 + jl;
    wkvmT[(size_t)l * 1048576 + (size_t)c * 1024 + r] = f2bf(wv * lnmg[l * 1024 + r]);
    wlatT[(size_t)l * 1572864 + (size_t)(512 + c) * 1024 + r] = f2bf(wv * lnlg[l * 1024 + r]);
  }
}

// Wq fold into wlatT cols [0,512): wlatT[l][c][r] = bf16(Wq[l][r][c]*lnlg*0.125)
// grid (16, 32, 6)
__global__ __launch_bounds__(256) void k_fold_q(const float* __restrict__ Wq,
    const float* __restrict__ lnlg, ushort* __restrict__ wlatT) {
  __shared__ float tile[32][33];
  int l = blockIdx.z;
  const float* Wl = Wq + (size_t)l * 524288;
  int r0 = blockIdx.y * 32, c0 = blockIdx.x * 32;
  int tx = threadIdx.x & 31, ty = threadIdx.x >> 5;
#pragma unroll
  for (int i = 0; i < 4; ++i)
    tile[ty + i * 8][tx] = Wl[(size_t)(r0 + ty + i * 8) * 512 + c0 + tx];
  __syncthreads();
#pragma unroll
  for (int i = 0; i < 4; ++i) {
    int jl = ty + i * 8;
    int r = r0 + tx, c = c0 + jl;
    wlatT[(size_t)l * 1572864 + (size_t)c * 1024 + r] =
        f2bf(tile[tx][jl] * lnlg[l * 1024 + r] * 0.125f);
  }
}

// Wout transpose: woutT[l][c][r] = bf16(Wout[l][r][c]), R=512, C=1024
// grid (32, 16, 6)
__global__ __launch_bounds__(256) void k_fold_out(const float* __restrict__ Wout,
    ushort* __restrict__ woutT) {
  __shared__ float tile[32][33];
  int l = blockIdx.z;
  const float* Wl = Wout + (size_t)l * 524288;
  int r0 = blockIdx.y * 32, c0 = blockIdx.x * 32;
  int tx = threadIdx.x & 31, ty = threadIdx.x >> 5;
#pragma unroll
  for (int i = 0; i < 4; ++i)
    tile[ty + i * 8][tx] = Wl[(size_t)(r0 + ty + i * 8) * 1024 + c0 + tx];
  __syncthreads();
#pragma unroll
  for (int i = 0; i < 4; ++i) {
    int jl = ty + i * 8;
    woutT[(size_t)l * 524288 + (size_t)(c0 + jl) * 512 + r0 + tx] = f2bf(tile[tx][jl]);
  }
}

// ---------------------------------------------------------------------------
// Bias rows. 2560 cols total: [0,1024) bkvm; [1024,1536) blat q (x0.125);
// [1536,2560) blat kv-part (+512 offset). grid (40,6), block 256.
__global__ __launch_bounds__(256) void k_bias(const float* __restrict__ Wkv,
    const float* __restrict__ Wq, const float* __restrict__ lnmb,
    const float* __restrict__ lnlb, float* __restrict__ bkvm,
    float* __restrict__ blat) {
  __shared__ float red[4][64];
  int l = blockIdx.y;
  int c0 = blockIdx.x * 64;
  int tx = threadIdx.x & 63, dg = threadIdx.x >> 6;
  const float* Wsrc; const float* bv; int ld; float scale = 1.0f; float* outp;
  if (c0 < 1024) {
    Wsrc = Wkv + (size_t)l * 1048576 + c0 + tx; bv = lnmb + l * 1024; ld = 1024;
    outp = bkvm + l * 1024 + c0 + tx;
  } else if (c0 < 1536) {
    Wsrc = Wq + (size_t)l * 524288 + (c0 - 1024) + tx; bv = lnlb + l * 1024; ld = 512;
    outp = blat + l * 1536 + (c0 - 1024) + tx; scale = 0.125f;
  } else {
    Wsrc = Wkv + (size_t)l * 1048576 + (c0 - 1536) + tx; bv = lnlb + l * 1024; ld = 1024;
    outp = blat + l * 1536 + 512 + (c0 - 1536) + tx;
  }
  float acc = 0.f;
  for (int d = dg * 256; d < dg * 256 + 256; ++d)
    acc += bv[d] * Wsrc[(size_t)d * ld];
  red[dg][tx] = acc;
  __syncthreads();
  if (dg == 0) *outp = (red[0][tx] + red[1][tx] + red[2][tx] + red[3][tx]) * scale;
}

// ---------------------------------------------------------------------------
__global__ __launch_bounds__(256) void k_rownorm(const float* __restrict__ in,
    const float* __restrict__ pos, ushort* __restrict__ out) {
  int row = blockIdx.x, t = threadIdx.x;
  float4 v = *(const float4*)(in + (size_t)row * 1024 + t * 4);
  if (pos) {
    float4 p = *(const float4*)(pos + (size_t)(row & 511) * 1024 + t * 4);
    v.x += p.x; v.y += p.y; v.z += p.z; v.w += p.w;
  }
  float s = v.x + v.y + v.z + v.w;
  float q = v.x * v.x + v.y * v.y + v.z * v.z + v.w * v.w;
#pragma unroll
  for (int off = 32; off; off >>= 1) { s += __shfl_xor(s, off); q += __shfl_xor(q, off); }
  __shared__ float rs[4], rq[4];
  if ((t & 63) == 0) { rs[t >> 6] = s; rq[t >> 6] = q; }
  __syncthreads();
  s = rs[0] + rs[1] + rs[2] + rs[3];
  q = rq[0] + rq[1] + rq[2] + rq[3];
  float mean = s * (1.0f / 1024.0f);
  float var = q * (1.0f / 1024.0f) - mean * mean;
  float rstd = rsqrtf(var + 1e-5f);
  ushort4 o;
  o.x = f2bf((v.x - mean) * rstd);
  o.y = f2bf((v.y - mean) * rstd);
  o.z = f2bf((v.z - mean) * rstd);
  o.w = f2bf((v.w - mean) * rstd);
  *(ushort4*)(out + (size_t)row * 1024 + t * 4) = o;
}

__global__ __launch_bounds__(256) void k_finalln(const float* __restrict__ in,
    const float* __restrict__ g, const float* __restrict__ b, float* __restrict__ out) {
  int row = blockIdx.x, t = threadIdx.x;
  float4 v = *(const float4*)(in + (size_t)row * 1024 + t * 4);
  float s = v.x + v.y + v.z + v.w;
  float q = v.x * v.x + v.y * v.y + v.z * v.z + v.w * v.w;
#pragma unroll
  for (int off = 32; off; off >>= 1) { s += __shfl_xor(s, off); q += __shfl_xor(q, off); }
  __shared__ float rs[4], rq[4];
  if ((t & 63) == 0) { rs[t >> 6] = s; rq[t >> 6] = q; }
  __syncthreads();
  s = rs[0] + rs[1] + rs[2] + rs[3];
  q = rq[0] + rq[1] + rq[2] + rq[3];
  float mean = s * (1.0f / 1024.0f);
  float var = q * (1.0f / 1024.0f) - mean * mean;
  float rstd = rsqrtf(var + 1e-5f);
  float4 g4 = *(const float4*)(g + t * 4);
  float4 b4 = *(const float4*)(b + t * 4);
  float4 o;
  o.x = (v.x - mean) * rstd * g4.x + b4.x;
  o.y = (v.y - mean) * rstd * g4.y + b4.y;
  o.z = (v.z - mean) * rstd * g4.z + b4.z;
  o.w = (v.w - mean) * rstd * g4.w + b4.w;
  *(float4*)(out + (size_t)row * 1024 + t * 4) = o;
}

__global__ __launch_bounds__(256) void k_latinit(const float* __restrict__ latents,
                                                 float* __restrict__ lat) {
  int row = blockIdx.x, t = threadIdx.x;
  *(float4*)(lat + (size_t)row * 1024 + t * 4) =
      *(const float4*)(latents + (size_t)(row & 63) * 1024 + t * 4);
}

// ---------------------------------------------------------------------------
// 2-phase double-buffered 128^2 GEMM (media KV). MODE 1 epilogue:
// row -> b=row>>9, jr=64+(row&511); col<512 -> K else V. N must be 1024.
__global__ __launch_bounds__(256) void k_gemm128m(const ushort* __restrict__ A,
    const ushort* __restrict__ Bt, const float* __restrict__ bias,
    ushort* __restrict__ Kb, ushort* __restrict__ Vb, int K) {
  __shared__ ushort Al[2][128][32];
  __shared__ ushort Bl[2][128][32];
  int tid = threadIdx.x, lane = tid & 63, w = tid >> 6;
  int wr = w >> 1, wc = w & 1;
  int m0 = blockIdx.y * 128, n0 = blockIdx.x * 128;
  f32x4 acc[4][4] = {};
  const ushort* Ag = A + (size_t)(m0 + w * 32 + (lane >> 2)) * K + (lane & 3) * 8;
  const ushort* Bg = Bt + (size_t)(n0 + w * 32 + (lane >> 2)) * K + (lane & 3) * 8;
  int fr = lane & 15, fk = (lane >> 4) << 3;
  int nt = K >> 5;
  // prologue: tile 0 -> buf 0
  gld16(&Al[0][w * 32][0], Ag);
  gld16(&Al[0][w * 32 + 16][0], Ag + (size_t)16 * K);
  gld16(&Bl[0][w * 32][0], Bg);
  gld16(&Bl[0][w * 32 + 16][0], Bg + (size_t)16 * K);
  __syncthreads();
  for (int t = 0; t < nt; ++t) {
    int cur = t & 1;
    if (t + 1 < nt) {                    // stage NEXT tile first (overlap)
      int k0 = (t + 1) << 5;
      gld16(&Al[cur ^ 1][w * 32][0], Ag + k0);
      gld16(&Al[cur ^ 1][w * 32 + 16][0], Ag + k0 + (size_t)16 * K);
      gld16(&Bl[cur ^ 1][w * 32][0], Bg + k0);
      gld16(&Bl[cur ^ 1][w * 32 + 16][0], Bg + k0 + (size_t)16 * K);
    }
    short8_t a[4], b[4];
#pragma unroll
    for (int mt = 0; mt < 4; ++mt)
      a[mt] = *(const short8_t*)&Al[cur][wr * 64 + mt * 16 + fr][fk];
#pragma unroll
    for (int nt2 = 0; nt2 < 4; ++nt2)
      b[nt2] = *(const short8_t*)&Bl[cur][wc * 64 + nt2 * 16 + fr][fk];
#pragma unroll
    for (int mt = 0; mt < 4; ++mt)
#pragma unroll
      for (int nt2 = 0; nt2 < 4; ++nt2)
        acc[mt][nt2] = mfma16(a[mt], b[nt2], acc[mt][nt2]);
    __syncthreads();                     // drains vmcnt(0): next tile landed
  }
#pragma unroll
  for (int mt = 0; mt < 4; ++mt)
#pragma unroll
    for (int nt2 = 0; nt2 < 4; ++nt2)
#pragma unroll
      for (int r = 0; r < 4; ++r) {
        int row = m0 + wr * 64 + mt * 16 + ((lane >> 4) << 2) + r;
        int col = n0 + wc * 64 + nt2 * 16 + (lane & 15);
        float v = acc[mt][nt2][r] + bias[col];
        int b_ = row >> 9;
        int jr = 64 + (row & 511);
        size_t base = ((size_t)(b_ * 576 + jr)) << 9;
        if (col < 512) Kb[base + col] = f2bf(v);
        else           Vb[base + col - 512] = f2bf(v);
      }
}

// ---------------------------------------------------------------------------
// 2-phase double-buffered 64^2 GEMM. 4 waves of 32x32.
// MODE 3: latent merged (col<512 q; <1024 K_lat; else V_lat), N=1536
// MODE 2: f32 residual += (out-proj), N arbitrary
template <int MODE>
__global__ __launch_bounds__(256) void k_gemm64(const ushort* __restrict__ A,
    const ushort* __restrict__ Bt, const float* __restrict__ bias,
    ushort* __restrict__ o0, ushort* __restrict__ o1, ushort* __restrict__ o2,
    float* __restrict__ of, int N, int K) {
  __shared__ ushort Al[2][64][32];
  __shared__ ushort Bl[2][64][32];
  int tid = threadIdx.x, lane = tid & 63, w = tid >> 6;
  int wr = w >> 1, wc = w & 1;
  int m0 = blockIdx.y * 64, n0 = blockIdx.x * 64;
  f32x4 acc[2][2] = {};
  const ushort* Ag = A + (size_t)(m0 + w * 16 + (lane >> 2)) * K + (lane & 3) * 8;
  const ushort* Bg = Bt + (size_t)(n0 + w * 16 + (lane >> 2)) * K + (lane & 3) * 8;
  int fr = lane & 15, fk = (lane >> 4) << 3;
  int nt = K >> 5;
  gld16(&Al[0][w * 16][0], Ag);
  gld16(&Bl[0][w * 16][0], Bg);
  __syncthreads();
  for (int t = 0; t < nt; ++t) {
    int cur = t & 1;
    if (t + 1 < nt) {
      int k0 = (t + 1) << 5;
      gld16(&Al[cur ^ 1][w * 16][0], Ag + k0);
      gld16(&Bl[cur ^ 1][w * 16][0], Bg + k0);
    }
    short8_t a[2], b[2];
#pragma unroll
    for (int mt = 0; mt < 2; ++mt)
      a[mt] = *(const short8_t*)&Al[cur][wr * 32 + mt * 16 + fr][fk];
#pragma unroll
    for (int nt2 = 0; nt2 < 2; ++nt2)
      b[nt2] = *(const short8_t*)&Bl[cur][wc * 32 + nt2 * 16 + fr][fk];
#pragma unroll
    for (int mt = 0; mt < 2; ++mt)
#pragma unroll
      for (int nt2 = 0; nt2 < 2; ++nt2)
        acc[mt][nt2] = mfma16(a[mt], b[nt2], acc[mt][nt2]);
    __syncthreads();
  }
#pragma unroll
  for (int mt = 0; mt < 2; ++mt)
#pragma unroll
    for (int nt2 = 0; nt2 < 2; ++nt2)
#pragma unroll
      for (int r = 0; r < 4; ++r) {
        int row = m0 + wr * 32 + mt * 16 + ((lane >> 4) << 2) + r;
        int col = n0 + wc * 32 + nt2 * 16 + (lane & 15);
        float v = acc[mt][nt2][r] + (bias ? bias[col] : 0.0f);
        if constexpr (MODE == 3) {
          int b_ = row >> 6, i = row & 63;
          if (col < 512) {
            o0[(size_t)row * 512 + col] = f2bf(v);
          } else if (col < 1024) {
            o1[(((size_t)(b_ * 576 + i)) << 9) + (col - 512)] = f2bf(v);
          } else {
            o2[(((size_t)(b_ * 576 + i)) << 9) + (col - 1024)] = f2bf(v);
          }
        } else {
          of[(size_t)row * N + col] += v;
        }
      }
}

// ---------------------------------------------------------------------------
// Fused attention (unchanged from round 1). Block = (b, h, 32-row half).
__global__ __launch_bounds__(256) void k_attn(const ushort* __restrict__ Q,
    const ushort* __restrict__ Kb, const ushort* __restrict__ Vb,
    const int* __restrict__ amask, ushort* __restrict__ AO) {
  __shared__ ushort sim[32][584];
  __shared__ ushort kt[64][72];
  int blk = blockIdx.x;
  int half = blk & 1, h = (blk >> 1) & 7, b = blk >> 4;
  int tid = threadIdx.x, lane = tid & 63, w = tid >> 6;
  int wr = w >> 1, wc = w & 1;
  short8_t aq0, aq1;
  {
    int qi = half * 32 + wr * 16 + (lane & 15);
    const ushort* qp = Q + ((size_t)(b * 64 + qi) << 9) + h * 64 + ((lane >> 4) << 3);
    aq0 = *(const short8_t*)qp;
    aq1 = *(const short8_t*)(qp + 32);
  }
  int sr = tid >> 2, scol = (tid & 3) << 4;
  for (int jt = 0; jt < 9; ++jt) {
    const ushort* kp = Kb + ((size_t)(b * 576 + jt * 64 + sr) << 9) + h * 64 + scol;
    short8_t k0 = *(const short8_t*)kp;
    short8_t k1 = *(const short8_t*)(kp + 8);
    __syncthreads();
    *(short8_t*)&kt[sr][scol] = k0;
    *(short8_t*)&kt[sr][scol + 8] = k1;
    __syncthreads();
#pragma unroll
    for (int c2 = 0; c2 < 2; ++c2) {
      int ct = wc * 2 + c2;
      f32x4 acc = {};
      short8_t bk0 = *(const short8_t*)&kt[ct * 16 + (lane & 15)][(lane >> 4) << 3];
      short8_t bk1 = *(const short8_t*)&kt[ct * 16 + (lane & 15)][32 + ((lane >> 4) << 3)];
      acc = mfma16(aq0, bk0, acc);
      acc = mfma16(aq1, bk1, acc);
#pragma unroll
      for (int r = 0; r < 4; ++r)
        sim[wr * 16 + ((lane >> 4) << 2) + r][jt * 64 + ct * 16 + (lane & 15)] =
            f2bf(acc[r]);
    }
  }
  __syncthreads();
  unsigned mbits = 0;
#pragma unroll
  for (int c = 1; c < 9; ++c)
    if (amask[b * 512 + (c - 1) * 64 + lane]) mbits |= (1u << c);
  for (int rr = 0; rr < 8; ++rr) {
    int row = w * 8 + rr;
    float vals[9];
    float m = -3.0e38f;
#pragma unroll
    for (int c = 0; c < 9; ++c) {
      float v = bf2f(sim[row][c * 64 + lane]);
      vals[c] = v;
      if (!((mbits >> c) & 1)) m = fmaxf(m, v);
    }
#pragma unroll
    for (int off = 32; off; off >>= 1) m = fmaxf(m, __shfl_xor(m, off));
    float ssum = 0.f;
    float p[9];
#pragma unroll
    for (int c = 0; c < 9; ++c) {
      p[c] = ((mbits >> c) & 1) ? 0.f : __expf(vals[c] - m);
      ssum += p[c];
    }
#pragma unroll
    for (int off = 32; off; off >>= 1) ssum += __shfl_xor(ssum, off);
    float inv = 1.0f / ssum;
#pragma unroll
    for (int c = 0; c < 9; ++c)
      sim[row][c * 64 + lane] = f2bf(p[c] * inv);
  }
  __syncthreads();
  f32x4 oacc[2] = {};
  for (int jt = 0; jt < 9; ++jt) {
    const ushort* vp = Vb + ((size_t)(b * 576 + jt * 64 + sr) << 9) + h * 64 + scol;
    short8_t v0 = *(const short8_t*)vp;
    short8_t v1 = *(const short8_t*)(vp + 8);
    __syncthreads();
#pragma unroll
    for (int e = 0; e < 8; ++e) kt[scol + e][sr] = (ushort)v0[e];
#pragma unroll
    for (int e = 0; e < 8; ++e) kt[scol + 8 + e][sr] = (ushort)v1[e];
    __syncthreads();
#pragma unroll
    for (int d2 = 0; d2 < 2; ++d2) {
      int dt = wc * 2 + d2;
      short8_t pa0 = *(const short8_t*)&sim[wr * 16 + (lane & 15)][jt * 64 + ((lane >> 4) << 3)];
      short8_t pa1 = *(const short8_t*)&sim[wr * 16 + (lane & 15)][jt * 64 + 32 + ((lane >> 4) << 3)];
      short8_t bv0 = *(const short8_t*)&kt[dt * 16 + (lane & 15)][(lane >> 4) << 3];
      short8_t bv1 = *(const short8_t*)&kt[dt * 16 + (lane & 15)][32 + ((lane >> 4) << 3)];
      oacc[d2] = mfma16(pa0, bv0, oacc[d2]);
      oacc[d2] = mfma16(pa1, bv1, oacc[d2]);
    }
  }
#pragma unroll
  for (int d2 = 0; d2 < 2; ++d2) {
    int dt = wc * 2 + d2;
#pragma unroll
    for (int r = 0; r < 4; ++r) {
      int i = half * 32 + wr * 16 + ((lane >> 4) << 2) + r;
      int d = dt * 16 + (lane & 15);
      AO[((size_t)(b * 64 + i) << 9) + h * 64 + d] = f2bf(oacc[d2][r]);
    }
  }
}

// ---------------------------------------------------------------------------
extern "C" void kernel_launch(void* const* d_in, const int* in_sizes, int n_in,
                              void* d_out, int out_size, void* d_ws, size_t ws_size,
                              hipStream_t stream) {
  const float* x       = (const float*)d_in[0];
  const int*   amask   = (const int*)d_in[1];
  const float* latents = (const float*)d_in[2];
  const float* pos     = (const float*)d_in[3];
  const float* lnmg    = (const float*)d_in[4];
  const float* lnmb    = (const float*)d_in[5];
  const float* lnlg    = (const float*)d_in[6];
  const float* lnlb    = (const float*)d_in[7];
  const float* Wq      = (const float*)d_in[8];
  const float* Wkv     = (const float*)d_in[9];
  const float* Wout    = (const float*)d_in[10];
  const float* fg      = (const float*)d_in[11];
  const float* fb      = (const float*)d_in[12];
  float* out = (float*)d_out;
  char* ws = (char*)d_ws;

  ushort* xhat  = (ushort*)(ws + 0);           // [16384][1024] bf16   32 MiB
  ushort* wkvmT = (ushort*)(ws + 33554432);    // [6][1024][1024]      12 MiB
  ushort* wlatT = (ushort*)(ws + 46137344);    // [6][1536][1024]      18 MiB
  ushort* woutT = (ushort*)(ws + 65011712);    // [6][1024][512]        6 MiB
  float*  bkvm  = (float*)(ws + 71303168);     // [6][1024]
  float*  blat  = (float*)(ws + 71327744);     // [6][1536]
  float*  lat   = (float*)(ws + 71364608);     // [2048][1024] f32      8 MiB
  ushort* lhat  = (ushort*)(ws + 79753216);    // [2048][1024] bf16     4 MiB
  ushort* qbuf  = (ushort*)(ws + 83947520);    // [2048][512]  bf16     2 MiB
  ushort* Kbuf  = (ushort*)(ws + 86044672);    // [32][576][512]       18 MiB
  ushort* Vbuf  = (ushort*)(ws + 104919040);   // [32][576][512]       18 MiB
  ushort* aobuf = (ushort*)(ws + 123793408);   // [2048][512]           2 MiB

  dim3 B256(256);
  k_fold_kv<<<dim3(32, 32, 6), B256, 0, stream>>>(Wkv, lnmg, lnlg, wkvmT, wlatT);
  k_fold_q<<<dim3(16, 32, 6), B256, 0, stream>>>(Wq, lnlg, wlatT);
  k_fold_out<<<dim3(32, 16, 6), B256, 0, stream>>>(Wout, woutT);
  k_bias<<<dim3(40, 6), B256, 0, stream>>>(Wkv, Wq, lnmb, lnlb, bkvm, blat);
  k_rownorm<<<16384, B256, 0, stream>>>(x, pos, xhat);
  k_latinit<<<2048, B256, 0, stream>>>(latents, lat);

  for (int l = 0; l < 6; ++l) {
    k_rownorm<<<2048, B256, 0, stream>>>(lat, nullptr, lhat);
    // merged latent GEMM: [q | K_lat | V_lat], N=1536, 768 blocks
    k_gemm64<3><<<dim3(24, 32), B256, 0, stream>>>(
        lhat, wlatT + (size_t)l * 1572864, blat + l * 1536,
        qbuf, Kbuf, Vbuf, nullptr, 1536, 1024);
    // media KV: 2-phase 128^2, grid (8,128)
    k_gemm128m<<<dim3(8, 128), B256, 0, stream>>>(
        xhat, wkvmT + (size_t)l * 1048576, bkvm + l * 1024, Kbuf, Vbuf, 1024);
    k_attn<<<512, B256, 0, stream>>>(qbuf, Kbuf, Vbuf, amask, aobuf);
    // lat += attn_out @ Wout, N=1024, K=512, 512 blocks
    k_gemm64<2><<<dim3(16, 32), B256, 0, stream>>>(
        aobuf, woutT + (size_t)l * 524288, nullptr,
        nullptr, nullptr, nullptr, lat, 1024, 512);
  }
  k_finalln<<<2048, B256, 0, stream>>>(lat, fg, fb, out);
}

// Round 4
// 762.992 us; speedup vs baseline: 1.6182x; 1.0058x over previous
//
#include <hip/hip_runtime.h>
#include <cstdint>

// ---------------------------------------------------------------------------
// PerceiverResampler on MI355X (gfx950) — round 4:
//  * media GEMM: XCD-ownership grid remap (A fetched once per HBM; B L2-resident)
//  * vectorized transposing epilogue -> K row-major, V transposed (Vt[b][d][j])
//  * attention: zero-staging — K and Vt fragments read directly from global,
//    2 barriers total (was ~38)
// B=32 SEQ=512 DIM=1024 DEPTH=6 HEADS=8 DHEAD=64 INNER=512 NLAT=64
// ---------------------------------------------------------------------------

#define DEVINL __device__ __forceinline__

typedef __attribute__((ext_vector_type(8))) short short8_t;   // 8 x bf16
typedef __attribute__((ext_vector_type(4))) float f32x4;

DEVINL ushort f2bf(float f) {
  union { float f; uint32_t u; } c; c.f = f;
  uint32_t u = c.u;
  u += ((u >> 16) & 1u) + 0x7fffu;
  return (ushort)(u >> 16);
}
DEVINL float bf2f(ushort u) {
  union { uint32_t u; float f; } c; c.u = ((uint32_t)u) << 16;
  return c.f;
}
DEVINL f32x4 mfma16(short8_t a, short8_t b, f32x4 c) {
  return __builtin_amdgcn_mfma_f32_16x16x32_bf16(a, b, c, 0, 0, 0);
}
DEVINL void gld16(ushort* lds, const ushort* g) {
  __builtin_amdgcn_global_load_lds(
      (const __attribute__((address_space(1))) void*)g,
      (__attribute__((address_space(3))) void*)lds, 16, 0, 0);
}

// ---------------------------------------------------------------------------
// Fused Wkv fold (one Wkv read): media transpose + latent part of wlatT.
__global__ __launch_bounds__(256) void k_fold_kv(const float* __restrict__ Wkv,
    const float* __restrict__ lnmg, const float* __restrict__ lnlg,
    ushort* __restrict__ wkvmT, ushort* __restrict__ wlatT) {
  __shared__ float tile[32][33];
  int l = blockIdx.z;
  const float* Wl = Wkv + (size_t)l * 1048576;
  int r0 = blockIdx.y * 32, c0 = blockIdx.x * 32;
  int tx = threadIdx.x & 31, ty = threadIdx.x >> 5;
#pragma unroll
  for (int i = 0; i < 4; ++i)
    tile[ty + i * 8][tx] = Wl[(size_t)(r0 + ty + i * 8) * 1024 + c0 + tx];
  __syncthreads();
#pragma unroll
  for (int i = 0; i < 4; ++i) {
    int jl = ty + i * 8;
    float wv = tile[tx][jl];
    int r = r0 + tx, c = c0 + jl;
    wkvmT[(size_t)l * 1048576 + (size_t)c * 1024 + r] = f2bf(wv * lnmg[l * 1024 + r]);
    wlatT[(size_t)l * 1572864 + (size_t)(512 + c) * 1024 + r] = f2bf(wv * lnlg[l * 1024 + r]);
  }
}

__global__ __launch_bounds__(256) void k_fold_q(const float* __restrict__ Wq,
    const float* __restrict__ lnlg, ushort* __restrict__ wlatT) {
  __shared__ float tile[32][33];
  int l = blockIdx.z;
  const float* Wl = Wq + (size_t)l * 524288;
  int r0 = blockIdx.y * 32, c0 = blockIdx.x * 32;
  int tx = threadIdx.x & 31, ty = threadIdx.x >> 5;
#pragma unroll
  for (int i = 0; i < 4; ++i)
    tile[ty + i * 8][tx] = Wl[(size_t)(r0 + ty + i * 8) * 512 + c0 + tx];
  __syncthreads();
#pragma unroll
  for (int i = 0; i < 4; ++i) {
    int jl = ty + i * 8;
    int r = r0 + tx, c = c0 + jl;
    wlatT[(size_t)l * 1572864 + (size_t)c * 1024 + r] =
        f2bf(tile[tx][jl] * lnlg[l * 1024 + r] * 0.125f);
  }
}

__global__ __launch_bounds__(256) void k_fold_out(const float* __restrict__ Wout,
    ushort* __restrict__ woutT) {
  __shared__ float tile[32][33];
  int l = blockIdx.z;
  const float* Wl = Wout + (size_t)l * 524288;
  int r0 = blockIdx.y * 32, c0 = blockIdx.x * 32;
  int tx = threadIdx.x & 31, ty = threadIdx.x >> 5;
#pragma unroll
  for (int i = 0; i < 4; ++i)
    tile[ty + i * 8][tx] = Wl[(size_t)(r0 + ty + i * 8) * 1024 + c0 + tx];
  __syncthreads();
#pragma unroll
  for (int i = 0; i < 4; ++i) {
    int jl = ty + i * 8;
    woutT[(size_t)l * 524288 + (size_t)(c0 + jl) * 512 + r0 + tx] = f2bf(tile[tx][jl]);
  }
}

// ---------------------------------------------------------------------------
__global__ __launch_bounds__(256) void k_bias(const float* __restrict__ Wkv,
    const float* __restrict__ Wq, const float* __restrict__ lnmb,
    const float* __restrict__ lnlb, float* __restrict__ bkvm,
    float* __restrict__ blat) {
  __shared__ float red[4][64];
  int l = blockIdx.y;
  int c0 = blockIdx.x * 64;
  int tx = threadIdx.x & 63, dg = threadIdx.x >> 6;
  const float* Wsrc; const float* bv; int ld; float scale = 1.0f; float* outp;
  if (c0 < 1024) {
    Wsrc = Wkv + (size_t)l * 1048576 + c0 + tx; bv = lnmb + l * 1024; ld = 1024;
    outp = bkvm + l * 1024 + c0 + tx;
  } else if (c0 < 1536) {
    Wsrc = Wq + (size_t)l * 524288 + (c0 - 1024) + tx; bv = lnlb + l * 1024; ld = 512;
    outp = blat + l * 1536 + (c0 - 1024) + tx; scale = 0.125f;
  } else {
    Wsrc = Wkv + (size_t)l * 1048576 + (c0 - 1536) + tx; bv = lnlb + l * 1024; ld = 1024;
    outp = blat + l * 1536 + 512 + (c0 - 1536) + tx;
  }
  float acc = 0.f;
  for (int d = dg * 256; d < dg * 256 + 256; ++d)
    acc += bv[d] * Wsrc[(size_t)d * ld];
  red[dg][tx] = acc;
  __syncthreads();
  if (dg == 0) *outp = (red[0][tx] + red[1][tx] + red[2][tx] + red[3][tx]) * scale;
}

// ---------------------------------------------------------------------------
__global__ __launch_bounds__(256) void k_rownorm(const float* __restrict__ in,
    const float* __restrict__ pos, ushort* __restrict__ out) {
  int row = blockIdx.x, t = threadIdx.x;
  float4 v = *(const float4*)(in + (size_t)row * 1024 + t * 4);
  if (pos) {
    float4 p = *(const float4*)(pos + (size_t)(row & 511) * 1024 + t * 4);
    v.x += p.x; v.y += p.y; v.z += p.z; v.w += p.w;
  }
  float s = v.x + v.y + v.z + v.w;
  float q = v.x * v.x + v.y * v.y + v.z * v.z + v.w * v.w;
#pragma unroll
  for (int off = 32; off; off >>= 1) { s += __shfl_xor(s, off); q += __shfl_xor(q, off); }
  __shared__ float rs[4], rq[4];
  if ((t & 63) == 0) { rs[t >> 6] = s; rq[t >> 6] = q; }
  __syncthreads();
  s = rs[0] + rs[1] + rs[2] + rs[3];
  q = rq[0] + rq[1] + rq[2] + rq[3];
  float mean = s * (1.0f / 1024.0f);
  float var = q * (1.0f / 1024.0f) - mean * mean;
  float rstd = rsqrtf(var + 1e-5f);
  ushort4 o;
  o.x = f2bf((v.x - mean) * rstd);
  o.y = f2bf((v.y - mean) * rstd);
  o.z = f2bf((v.z - mean) * rstd);
  o.w = f2bf((v.w - mean) * rstd);
  *(ushort4*)(out + (size_t)row * 1024 + t * 4) = o;
}

__global__ __launch_bounds__(256) void k_finalln(const float* __restrict__ in,
    const float* __restrict__ g, const float* __restrict__ b, float* __restrict__ out) {
  int row = blockIdx.x, t = threadIdx.x;
  float4 v = *(const float4*)(in + (size_t)row * 1024 + t * 4);
  float s = v.x + v.y + v.z + v.w;
  float q = v.x * v.x + v.y * v.y + v.z * v.z + v.w * v.w;
#pragma unroll
  for (int off = 32; off; off >>= 1) { s += __shfl_xor(s, off); q += __shfl_xor(q, off); }
  __shared__ float rs[4], rq[4];
  if ((t & 63) == 0) { rs[t >> 6] = s; rq[t >> 6] = q; }
  __syncthreads();
  s = rs[0] + rs[1] + rs[2] + rs[3];
  q = rq[0] + rq[1] + rq[2] + rq[3];
  float mean = s * (1.0f / 1024.0f);
  float var = q * (1.0f / 1024.0f) - mean * mean;
  float rstd = rsqrtf(var + 1e-5f);
  float4 g4 = *(const float4*)(g + t * 4);
  float4 b4 = *(const float4*)(b + t * 4);
  float4 o;
  o.x = (v.x - mean) * rstd * g4.x + b4.x;
  o.y = (v.y - mean) * rstd * g4.y + b4.y;
  o.z = (v.z - mean) * rstd * g4.z + b4.z;
  o.w = (v.w - mean) * rstd * g4.w + b4.w;
  *(float4*)(out + (size_t)row * 1024 + t * 4) = o;
}

__global__ __launch_bounds__(256) void k_latinit(const float* __restrict__ latents,
                                                 float* __restrict__ lat) {
  int row = blockIdx.x, t = threadIdx.x;
  *(float4*)(lat + (size_t)row * 1024 + t * 4) =
      *(const float4*)(latents + (size_t)(row & 63) * 1024 + t * 4);
}

// ---------------------------------------------------------------------------
// Media KV GEMM: 2-phase dbuf 128^2, XCD-ownership remap, LDS epilogue.
// A = xhat[16384][1024], Bt = wkvmT (N=1024), out: Kb rows / Vt transposed.
__global__ __launch_bounds__(256) void k_gemm128m(const ushort* __restrict__ A,
    const ushort* __restrict__ Bt, const float* __restrict__ bias,
    ushort* __restrict__ Kb, ushort* __restrict__ Vt, int K) {
  __shared__ ushort Al[2][128][32];
  __shared__ ushort Bl[2][128][32];
  __shared__ ushort Cl[64][136];
  int tid = threadIdx.x, lane = tid & 63, w = tid >> 6;
  int wr = w >> 1, wc = w & 1;
  // XCD-ownership remap: xcd = bid&7 owns M-chunk [xcd*2048, +2048);
  // inner order: walk all 8 N-panels per M-panel (B stays L2-resident).
  int bid = blockIdx.x;
  int xcd = bid & 7, i = bid >> 3;
  int n0 = (i & 7) * 128;
  int m0 = (xcd * 16 + (i >> 3)) * 128;
  f32x4 acc[4][4] = {};
  const ushort* Ag = A + (size_t)(m0 + w * 32 + (lane >> 2)) * K + (lane & 3) * 8;
  const ushort* Bg = Bt + (size_t)(n0 + w * 32 + (lane >> 2)) * K + (lane & 3) * 8;
  int fr = lane & 15, fk = (lane >> 4) << 3;
  int nt = K >> 5;
  gld16(&Al[0][w * 32][0], Ag);
  gld16(&Al[0][w * 32 + 16][0], Ag + (size_t)16 * K);
  gld16(&Bl[0][w * 32][0], Bg);
  gld16(&Bl[0][w * 32 + 16][0], Bg + (size_t)16 * K);
  __syncthreads();
  for (int t = 0; t < nt; ++t) {
    int cur = t & 1;
    if (t + 1 < nt) {
      int k0 = (t + 1) << 5;
      gld16(&Al[cur ^ 1][w * 32][0], Ag + k0);
      gld16(&Al[cur ^ 1][w * 32 + 16][0], Ag + k0 + (size_t)16 * K);
      gld16(&Bl[cur ^ 1][w * 32][0], Bg + k0);
      gld16(&Bl[cur ^ 1][w * 32 + 16][0], Bg + k0 + (size_t)16 * K);
    }
    short8_t a[4], b[4];
#pragma unroll
    for (int mt = 0; mt < 4; ++mt)
      a[mt] = *(const short8_t*)&Al[cur][wr * 64 + mt * 16 + fr][fk];
#pragma unroll
    for (int nt2 = 0; nt2 < 4; ++nt2)
      b[nt2] = *(const short8_t*)&Bl[cur][wc * 64 + nt2 * 16 + fr][fk];
#pragma unroll
    for (int mt = 0; mt < 4; ++mt)
#pragma unroll
      for (int nt2 = 0; nt2 < 4; ++nt2)
        acc[mt][nt2] = mfma16(a[mt], b[nt2], acc[mt][nt2]);
    __syncthreads();
  }
  // epilogue: two 64-row passes through Cl; vectorized 16B stores.
  int b_ = m0 >> 9;
  int jr0 = 64 + (m0 & 511);
  bool isV = (n0 >= 512);
  for (int p = 0; p < 2; ++p) {
    if (p) __syncthreads();              // Cl readout of pass 0 complete
    if (wr == p) {
#pragma unroll
      for (int mt = 0; mt < 4; ++mt)
#pragma unroll
        for (int nt2 = 0; nt2 < 4; ++nt2)
#pragma unroll
          for (int r = 0; r < 4; ++r) {
            int rl = mt * 16 + ((lane >> 4) << 2) + r;       // 0..63
            int col = wc * 64 + nt2 * 16 + (lane & 15);      // 0..127
            Cl[rl][col] = f2bf(acc[mt][nt2][r] + bias[n0 + col]);
          }
    }
    __syncthreads();
    if (!isV) {
      // K rows: 64 rows x 16 chunks of 16B, coalesced
#pragma unroll
      for (int q = 0; q < 4; ++q) {
        int task = tid + q * 256;
        int rl = task >> 4, ck = task & 15;
        short8_t vv = *(const short8_t*)&Cl[rl][ck * 8];
        int jr = jr0 + p * 64 + rl;
        *(short8_t*)&Kb[(((size_t)(b_ * 576 + jr)) << 9) + n0 + ck * 8] = vv;
      }
    } else {
      // V transposed: 128 d-rows x 8 j-chunks of 16B
#pragma unroll
      for (int q = 0; q < 4; ++q) {
        int task = tid + q * 256;
        int jg = task & 7, d = task >> 3;
        short8_t vv;
#pragma unroll
        for (int e = 0; e < 8; ++e) vv[e] = (short)Cl[jg * 8 + e][d];
        int dg = n0 - 512 + d;
        int j = jr0 + p * 64 + jg * 8;
        *(short8_t*)&Vt[((size_t)(b_ * 512 + dg)) * 576 + j] = vv;
      }
    }
  }
}

// ---------------------------------------------------------------------------
// 2-phase dbuf 64^2 GEMM. MODE 3: latent merged (q | K_lat | V_lat->Vt).
// MODE 2: f32 residual += (out-proj).
template <int MODE>
__global__ __launch_bounds__(256) void k_gemm64(const ushort* __restrict__ A,
    const ushort* __restrict__ Bt, const float* __restrict__ bias,
    ushort* __restrict__ o0, ushort* __restrict__ o1, ushort* __restrict__ o2,
    float* __restrict__ of, int N, int K) {
  __shared__ ushort Al[2][64][32];
  __shared__ ushort Bl[2][64][32];
  __shared__ ushort Cl[64][72];
  int tid = threadIdx.x, lane = tid & 63, w = tid >> 6;
  int wr = w >> 1, wc = w & 1;
  int m0 = blockIdx.y * 64, n0 = blockIdx.x * 64;
  f32x4 acc[2][2] = {};
  const ushort* Ag = A + (size_t)(m0 + w * 16 + (lane >> 2)) * K + (lane & 3) * 8;
  const ushort* Bg = Bt + (size_t)(n0 + w * 16 + (lane >> 2)) * K + (lane & 3) * 8;
  int fr = lane & 15, fk = (lane >> 4) << 3;
  int nt = K >> 5;
  gld16(&Al[0][w * 16][0], Ag);
  gld16(&Bl[0][w * 16][0], Bg);
  __syncthreads();
  for (int t = 0; t < nt; ++t) {
    int cur = t & 1;
    if (t + 1 < nt) {
      int k0 = (t + 1) << 5;
      gld16(&Al[cur ^ 1][w * 16][0], Ag + k0);
      gld16(&Bl[cur ^ 1][w * 16][0], Bg + k0);
    }
    short8_t a[2], b[2];
#pragma unroll
    for (int mt = 0; mt < 2; ++mt)
      a[mt] = *(const short8_t*)&Al[cur][wr * 32 + mt * 16 + fr][fk];
#pragma unroll
    for (int nt2 = 0; nt2 < 2; ++nt2)
      b[nt2] = *(const short8_t*)&Bl[cur][wc * 32 + nt2 * 16 + fr][fk];
#pragma unroll
    for (int mt = 0; mt < 2; ++mt)
#pragma unroll
      for (int nt2 = 0; nt2 < 2; ++nt2)
        acc[mt][nt2] = mfma16(a[mt], b[nt2], acc[mt][nt2]);
    __syncthreads();
  }
  if constexpr (MODE == 3) {
    if (n0 >= 1024) {
      // V_lat -> Vt via LDS transpose
#pragma unroll
      for (int mt = 0; mt < 2; ++mt)
#pragma unroll
        for (int nt2 = 0; nt2 < 2; ++nt2)
#pragma unroll
          for (int r = 0; r < 4; ++r) {
            int rl = wr * 32 + mt * 16 + ((lane >> 4) << 2) + r;
            int col = wc * 32 + nt2 * 16 + (lane & 15);
            Cl[rl][col] = f2bf(acc[mt][nt2][r] + bias[n0 + col]);
          }
      __syncthreads();
      int b_ = m0 >> 6;
#pragma unroll
      for (int q = 0; q < 2; ++q) {
        int task = tid + q * 256;
        int jg = task & 7, d = task >> 3;
        short8_t vv;
#pragma unroll
        for (int e = 0; e < 8; ++e) vv[e] = (short)Cl[jg * 8 + e][d];
        *(short8_t*)&o2[((size_t)(b_ * 512 + (n0 - 1024) + d)) * 576 + jg * 8] = vv;
      }
      return;
    }
  }
#pragma unroll
  for (int mt = 0; mt < 2; ++mt)
#pragma unroll
    for (int nt2 = 0; nt2 < 2; ++nt2)
#pragma unroll
      for (int r = 0; r < 4; ++r) {
        int row = m0 + wr * 32 + mt * 16 + ((lane >> 4) << 2) + r;
        int col = n0 + wc * 32 + nt2 * 16 + (lane & 15);
        float v = acc[mt][nt2][r] + (bias ? bias[col] : 0.0f);
        if constexpr (MODE == 3) {
          int b_ = row >> 6, ii = row & 63;
          if (col < 512) o0[(size_t)row * 512 + col] = f2bf(v);
          else           o1[(((size_t)(b_ * 576 + ii)) << 9) + (col - 512)] = f2bf(v);
        } else {
          of[(size_t)row * N + col] += v;
        }
      }
}

// ---------------------------------------------------------------------------
// Fused attention, zero staging: K from Kb rows, V from Vt rows — direct
// global 16B fragment loads (L2-hot). 2 barriers total.
__global__ __launch_bounds__(256) void k_attn(const ushort* __restrict__ Q,
    const ushort* __restrict__ Kb, const ushort* __restrict__ Vt,
    const int* __restrict__ amask, ushort* __restrict__ AO) {
  __shared__ ushort sim[32][584];
  int blk = blockIdx.x;
  int half = blk & 1, h = (blk >> 1) & 7, b = blk >> 4;
  int tid = threadIdx.x, lane = tid & 63, w = tid >> 6;
  int wr = w >> 1, wc = w & 1;
  short8_t aq0, aq1;
  {
    int qi = half * 32 + wr * 16 + (lane & 15);
    const ushort* qp = Q + ((size_t)(b * 64 + qi) << 9) + h * 64 + ((lane >> 4) << 3);
    aq0 = *(const short8_t*)qp;
    aq1 = *(const short8_t*)(qp + 32);
  }
  // ---- QK^T: B-fragments straight from Kb
  const ushort* kbase = Kb + (((size_t)(b * 576)) << 9) + h * 64 + ((lane >> 4) << 3);
  for (int jt = 0; jt < 9; ++jt) {
#pragma unroll
    for (int c2 = 0; c2 < 2; ++c2) {
      int ct = wc * 2 + c2;
      const ushort* kp = kbase + (((size_t)(jt * 64 + ct * 16 + (lane & 15))) << 9);
      short8_t bk0 = *(const short8_t*)kp;
      short8_t bk1 = *(const short8_t*)(kp + 32);
      f32x4 acc = {};
      acc = mfma16(aq0, bk0, acc);
      acc = mfma16(aq1, bk1, acc);
#pragma unroll
      for (int r = 0; r < 4; ++r)
        sim[wr * 16 + ((lane >> 4) << 2) + r][jt * 64 + ct * 16 + (lane & 15)] =
            f2bf(acc[r]);
    }
  }
  __syncthreads();
  // ---- masked softmax (8 rows per wave)
  unsigned mbits = 0;
#pragma unroll
  for (int c = 1; c < 9; ++c)
    if (amask[b * 512 + (c - 1) * 64 + lane]) mbits |= (1u << c);
  for (int rr = 0; rr < 8; ++rr) {
    int row = w * 8 + rr;
    float vals[9];
    float m = -3.0e38f;
#pragma unroll
    for (int c = 0; c < 9; ++c) {
      float v = bf2f(sim[row][c * 64 + lane]);
      vals[c] = v;
      if (!((mbits >> c) & 1)) m = fmaxf(m, v);
    }
#pragma unroll
    for (int off = 32; off; off >>= 1) m = fmaxf(m, __shfl_xor(m, off));
    float ssum = 0.f;
    float p[9];
#pragma unroll
    for (int c = 0; c < 9; ++c) {
      p[c] = ((mbits >> c) & 1) ? 0.f : __expf(vals[c] - m);
      ssum += p[c];
    }
#pragma unroll
    for (int off = 32; off; off >>= 1) ssum += __shfl_xor(ssum, off);
    float inv = 1.0f / ssum;
#pragma unroll
    for (int c = 0; c < 9; ++c)
      sim[row][c * 64 + lane] = f2bf(p[c] * inv);
  }
  __syncthreads();
  // ---- PV: A from sim (ds_read_b128), B straight from Vt
  f32x4 oacc[2] = {};
  const ushort* vbase = Vt + ((size_t)(b * 512 + h * 64)) * 576 + ((lane >> 4) << 3);
  for (int jt = 0; jt < 9; ++jt) {
    short8_t pa0 = *(const short8_t*)&sim[wr * 16 + (lane & 15)][jt * 64 + ((lane >> 4) << 3)];
    short8_t pa1 = *(const short8_t*)&sim[wr * 16 + (lane & 15)][jt * 64 + 32 + ((lane >> 4) << 3)];
#pragma unroll
    for (int d2 = 0; d2 < 2; ++d2) {
      int dt = wc * 2 + d2;
      const ushort* vp = vbase + (size_t)(dt * 16 + (lane & 15)) * 576 + jt * 64;
      short8_t bv0 = *(const short8_t*)vp;
      short8_t bv1 = *(const short8_t*)(vp + 32);
      oacc[d2] = mfma16(pa0, bv0, oacc[d2]);
      oacc[d2] = mfma16(pa1, bv1, oacc[d2]);
    }
  }
#pragma unroll
  for (int d2 = 0; d2 < 2; ++d2) {
    int dt = wc * 2 + d2;
#pragma unroll
    for (int r = 0; r < 4; ++r) {
      int i = half * 32 + wr * 16 + ((lane >> 4) << 2) + r;
      int d = dt * 16 + (lane & 15);
      AO[((size_t)(b * 64 + i) << 9) + h * 64 + d] = f2bf(oacc[d2][r]);
    }
  }
}

// ---------------------------------------------------------------------------
extern "C" void kernel_launch(void* const* d_in, const int* in_sizes, int n_in,
                              void* d_out, int out_size, void* d_ws, size_t ws_size,
                              hipStream_t stream) {
  const float* x       = (const float*)d_in[0];
  const int*   amask   = (const int*)d_in[1];
  const float* latents = (const float*)d_in[2];
  const float* pos     = (const float*)d_in[3];
  const float* lnmg    = (const float*)d_in[4];
  const float* lnmb    = (const float*)d_in[5];
  const float* lnlg    = (const float*)d_in[6];
  const float* lnlb    = (const float*)d_in[7];
  const float* Wq      = (const float*)d_in[8];
  const float* Wkv     = (const float*)d_in[9];
  const float* Wout    = (const float*)d_in[10];
  const float* fg      = (const float*)d_in[11];
  const float* fb      = (const float*)d_in[12];
  float* out = (float*)d_out;
  char* ws = (char*)d_ws;

  ushort* xhat  = (ushort*)(ws + 0);           // [16384][1024] bf16   32 MiB
  ushort* wkvmT = (ushort*)(ws + 33554432);    // [6][1024][1024]      12 MiB
  ushort* wlatT = (ushort*)(ws + 46137344);    // [6][1536][1024]      18 MiB
  ushort* woutT = (ushort*)(ws + 65011712);    // [6][1024][512]        6 MiB
  float*  bkvm  = (float*)(ws + 71303168);     // [6][1024]
  float*  blat  = (float*)(ws + 71327744);     // [6][1536]
  float*  lat   = (float*)(ws + 71364608);     // [2048][1024] f32      8 MiB
  ushort* lhat  = (ushort*)(ws + 79753216);    // [2048][1024] bf16     4 MiB
  ushort* qbuf  = (ushort*)(ws + 83947520);    // [2048][512]  bf16     2 MiB
  ushort* Kbuf  = (ushort*)(ws + 86044672);    // [32][576][512]       18 MiB
  ushort* Vt    = (ushort*)(ws + 104919040);   // [32][512][576]       18 MiB
  ushort* aobuf = (ushort*)(ws + 123793408);   // [2048][512]           2 MiB

  dim3 B256(256);
  k_fold_kv<<<dim3(32, 32, 6), B256, 0, stream>>>(Wkv, lnmg, lnlg, wkvmT, wlatT);
  k_fold_q<<<dim3(16, 32, 6), B256, 0, stream>>>(Wq, lnlg, wlatT);
  k_fold_out<<<dim3(32, 16, 6), B256, 0, stream>>>(Wout, woutT);
  k_bias<<<dim3(40, 6), B256, 0, stream>>>(Wkv, Wq, lnmb, lnlb, bkvm, blat);
  k_rownorm<<<16384, B256, 0, stream>>>(x, pos, xhat);
  k_latinit<<<2048, B256, 0, stream>>>(latents, lat);

  for (int l = 0; l < 6; ++l) {
    k_rownorm<<<2048, B256, 0, stream>>>(lat, nullptr, lhat);
    // merged latent GEMM: [q | K_lat | V_lat], N=1536
    k_gemm64<3><<<dim3(24, 32), B256, 0, stream>>>(
        lhat, wlatT + (size_t)l * 1572864, blat + l * 1536,
        qbuf, Kbuf, Vt, nullptr, 1536, 1024);
    // media KV: 2-phase 128^2, XCD-ownership remap, 1024 blocks
    k_gemm128m<<<dim3(1024), B256, 0, stream>>>(
        xhat, wkvmT + (size_t)l * 1048576, bkvm + l * 1024, Kbuf, Vt, 1024);
    k_attn<<<512, B256, 0, stream>>>(qbuf, Kbuf, Vt, amask, aobuf);
    // lat += attn_out @ Wout
    k_gemm64<2><<<dim3(16, 32), B256, 0, stream>>>(
        aobuf, woutT + (size_t)l * 524288, nullptr,
        nullptr, nullptr, nullptr, lat, 1024, 512);
  }
  k_finalln<<<2048, B256, 0, stream>>>(lat, fg, fb, out);
}

// Round 5
// 723.663 us; speedup vs baseline: 1.7061x; 1.0543x over previous
//
#include <hip/hip_runtime.h>
#include <cstdint>

// ---------------------------------------------------------------------------
// PerceiverResampler on MI355X (gfx950) — round 5:
//  * media KV GEMM rebuilt: 256x256 tile, 8 waves, BK=64, 160KiB LDS
//    (3 A-bufs + 2 B-bufs), counted vmcnt(4) per K-tile (never 0 in steady
//    state), raw s_barriers, XOR-swizzled LDS (chunk ^= row&7, both sides),
//    setprio around MFMA, 4-phase interleave. T2+T3+T4+T5 per the gate table.
//  * everything else identical to round 4 (isolate the change).
// B=32 SEQ=512 DIM=1024 DEPTH=6 HEADS=8 DHEAD=64 INNER=512 NLAT=64
// ---------------------------------------------------------------------------

#define DEVINL __device__ __forceinline__

typedef __attribute__((ext_vector_type(8))) short short8_t;   // 8 x bf16
typedef __attribute__((ext_vector_type(4))) float f32x4;

DEVINL ushort f2bf(float f) {
  union { float f; uint32_t u; } c; c.f = f;
  uint32_t u = c.u;
  u += ((u >> 16) & 1u) + 0x7fffu;
  return (ushort)(u >> 16);
}
DEVINL float bf2f(ushort u) {
  union { uint32_t u; float f; } c; c.u = ((uint32_t)u) << 16;
  return c.f;
}
DEVINL f32x4 mfma16(short8_t a, short8_t b, f32x4 c) {
  return __builtin_amdgcn_mfma_f32_16x16x32_bf16(a, b, c, 0, 0, 0);
}
DEVINL void gld16(ushort* lds, const ushort* g) {
  __builtin_amdgcn_global_load_lds(
      (const __attribute__((address_space(1))) void*)g,
      (__attribute__((address_space(3))) void*)lds, 16, 0, 0);
}

// ---------------------------------------------------------------------------
// Media KV GEMM: C[16384,1024] = xhat @ wkvmT^T + bias -> Kb rows / Vt cols.
// 256x256 tile, 512 thr (8 waves, 2M x 4N), BK=64, K=1024 (16 K-tiles).
// LDS (dynamic, 160KiB exactly):
//   A: 3 bufs @ 0, 32768, 65536      (tile t uses buf t%3)
//   B: 2 bufs @ 98304, 131072        (tile t uses buf t&1)
// Swizzle: 16B-chunk index ^= (row&7) — involution; staged via pre-swizzled
// global source (linear gld dest), read via swizzled ds_read addr.
// Schedule per tile t (phases q0..q3):
//   q0: vmcnt(4 | 0-at-tail); barrier; read b-frags(8)+a-frags(4);
//       issue B(t+1,h0); lgkm0; prio1; 16 MFMA; prio0; barrier
//   q1: a-frags; issue B(t+1,h1); ...   q2: issue A(t+2,h0); q3: A(t+2,h1)
// Steady state in-flight: 4-8 loads; one counted wait per tile.
__global__ __launch_bounds__(512, 2) void k_gemm256m(const ushort* __restrict__ A,
    const ushort* __restrict__ Bt, const float* __restrict__ bias,
    ushort* __restrict__ Kb, ushort* __restrict__ Vt) {
  extern __shared__ char lds[];
  constexpr int K = 1024, NT = 16;
  int tid = threadIdx.x, lane = tid & 63, w = tid >> 6;
  int wm = w >> 2, wn = w & 3;
  int fr = lane & 15;
  int fkb = (lane >> 4) << 4;            // fragment k-offset (bytes)
  int xorv = (fr & 7) << 4;              // read-side swizzle
  int bid = blockIdx.x;
  int xcd = bid & 7, ii = bid >> 3;      // XCD owns contiguous M-chunk
  int m0 = (xcd * 8 + (ii >> 2)) * 256;
  int n0 = (ii & 3) * 256;
  // staging constants (pre-swizzled source: chunk_src = (lane&7)^(lane>>3))
  int srow = w * 8 + (lane >> 3);
  int sce = ((lane & 7) ^ (lane >> 3)) << 3;
  const ushort* Ag = A + (size_t)(m0 + srow) * K + sce;
  const ushort* Bg = Bt + (size_t)(n0 + srow) * K + sce;
  f32x4 acc[8][4] = {};

  auto stA = [&](int t, int h) {
    ushort* d = (ushort*)(lds + (t % 3) * 32768 + h * 16384 + w * 1024);
    const ushort* s = Ag + (size_t)(h * 128) * K + t * 64;
    gld16(d, s);
    gld16((ushort*)((char*)d + 8192), s + (size_t)64 * K);
  };
  auto stB = [&](int t, int h) {
    ushort* d = (ushort*)(lds + 98304 + (t & 1) * 32768 + h * 16384 + w * 1024);
    const ushort* s = Bg + (size_t)(h * 128) * K + t * 64;
    gld16(d, s);
    gld16((ushort*)((char*)d + 8192), s + (size_t)64 * K);
  };
  // prologue: A(0), B(0), A(1) in canonical order -> 12 loads
  stA(0, 0); stA(0, 1); stB(0, 0); stB(0, 1); stA(1, 0); stA(1, 1);

#define PHASE(MQ, STAGE_STMT)                                                  \
  do {                                                                         \
    _Pragma("unroll") for (int m2 = 0; m2 < 2; ++m2)                           \
      _Pragma("unroll") for (int kh = 0; kh < 2; ++kh)                         \
        afr[m2][kh] = *(const short8_t*)(ab +                                  \
            ((wm * 128 + (MQ + m2) * 16 + fr) << 7) +                          \
            ((kh * 64 + fkb) ^ xorv));                                         \
    STAGE_STMT;                                                                \
    asm volatile("s_waitcnt lgkmcnt(0)" ::: "memory");                         \
    __builtin_amdgcn_s_setprio(1);                                             \
    _Pragma("unroll") for (int m2 = 0; m2 < 2; ++m2)                           \
      _Pragma("unroll") for (int nt = 0; nt < 4; ++nt)                         \
        _Pragma("unroll") for (int kh = 0; kh < 2; ++kh)                       \
          acc[MQ + m2][nt] = mfma16(afr[m2][kh], bfr[nt][kh], acc[MQ + m2][nt]); \
    __builtin_amdgcn_s_setprio(0);                                             \
    __builtin_amdgcn_s_barrier();                                              \
  } while (0)

  for (int t = 0; t < NT; ++t) {
    const char* ab = lds + (t % 3) * 32768;
    const char* bb = lds + 98304 + (t & 1) * 32768;
    short8_t bfr[4][2], afr[2][2];
    // tile-t data (A issued 2 tiles ago, B 1 tile ago) must be landed;
    // outstanding beyond = A(t+1) = 4 loads (0 at tail).
    if (t + 1 < NT) asm volatile("s_waitcnt vmcnt(4)" ::: "memory");
    else            asm volatile("s_waitcnt vmcnt(0)" ::: "memory");
    __builtin_amdgcn_s_barrier();
#pragma unroll
    for (int nt = 0; nt < 4; ++nt)
#pragma unroll
      for (int kh = 0; kh < 2; ++kh)
        bfr[nt][kh] = *(const short8_t*)(bb +
            ((wn * 64 + nt * 16 + fr) << 7) + ((kh * 64 + fkb) ^ xorv));
    PHASE(0, { if (t + 1 < NT) stB(t + 1, 0); });
    PHASE(2, { if (t + 1 < NT) stB(t + 1, 1); });
    PHASE(4, { if (t + 2 < NT) stA(t + 2, 0); });
    PHASE(6, { if (t + 2 < NT) stA(t + 2, 1); });
  }
#undef PHASE

  // ---- epilogue: reuse LDS as C-stage [128][264]; 2 passes of 128 rows.
  __syncthreads();
  ushort* Cl = (ushort*)lds;
  constexpr int CLS = 264;
  for (int p = 0; p < 2; ++p) {
    if (p) __syncthreads();
    if (wm == p) {
#pragma unroll
      for (int mt = 0; mt < 8; ++mt)
#pragma unroll
        for (int nt = 0; nt < 4; ++nt)
#pragma unroll
          for (int r = 0; r < 4; ++r) {
            int rl = mt * 16 + ((lane >> 4) << 2) + r;
            int cl = wn * 64 + nt * 16 + (lane & 15);
            Cl[rl * CLS + cl] = f2bf(acc[mt][nt][r] + bias[n0 + cl]);
          }
    }
    __syncthreads();
    int rowg0 = m0 + p * 128;
    int b_ = rowg0 >> 9;
    int jbase = 64 + (rowg0 & 511);
    if (n0 < 512) {
      // K panel: 128 rows x 32 chunks of 16B... (256 cols = 32 chunks)
#pragma unroll
      for (int q2 = 0; q2 < 8; ++q2) {
        int task = tid + q2 * 512;          // 4096 tasks: 128 rows x 32 chunks
        int rl = task >> 5, ck = task & 31;
        short8_t vv = *(const short8_t*)&Cl[rl * CLS + ck * 8];
        *(short8_t*)&Kb[((size_t)(b_ * 576 + jbase + rl) << 9) + n0 + ck * 8] = vv;
      }
    } else {
      // V panel -> Vt[b][d][j]: 256 d x 16 j-chunks of 8
#pragma unroll
      for (int q2 = 0; q2 < 8; ++q2) {
        int task = tid + q2 * 512;          // 4096 tasks
        int d = task >> 4, jg = task & 15;
        short8_t vv;
#pragma unroll
        for (int e = 0; e < 8; ++e) vv[e] = (short)Cl[(jg * 8 + e) * CLS + d];
        *(short8_t*)&Vt[((size_t)(b_ * 512 + (n0 - 512) + d)) * 576 +
                        jbase + jg * 8] = vv;
      }
    }
  }
}

// ---------------------------------------------------------------------------
// Fused Wkv fold (one Wkv read): media transpose + latent part of wlatT.
__global__ __launch_bounds__(256) void k_fold_kv(const float* __restrict__ Wkv,
    const float* __restrict__ lnmg, const float* __restrict__ lnlg,
    ushort* __restrict__ wkvmT, ushort* __restrict__ wlatT) {
  __shared__ float tile[32][33];
  int l = blockIdx.z;
  const float* Wl = Wkv + (size_t)l * 1048576;
  int r0 = blockIdx.y * 32, c0 = blockIdx.x * 32;
  int tx = threadIdx.x & 31, ty = threadIdx.x >> 5;
#pragma unroll
  for (int i = 0; i < 4; ++i)
    tile[ty + i * 8][tx] = Wl[(size_t)(r0 + ty + i * 8) * 1024 + c0 + tx];
  __syncthreads();
#pragma unroll
  for (int i = 0; i < 4; ++i) {
    int jl = ty + i * 8;
    float wv = tile[tx][jl];
    int r = r0 + tx, c = c0 + jl;
    wkvmT[(size_t)l * 1048576 + (size_t)c * 1024 + r] = f2bf(wv * lnmg[l * 1024 + r]);
    wlatT[(size_t)l * 1572864 + (size_t)(512 + c) * 1024 + r] = f2bf(wv * lnlg[l * 1024 + r]);
  }
}

__global__ __launch_bounds__(256) void k_fold_q(const float* __restrict__ Wq,
    const float* __restrict__ lnlg, ushort* __restrict__ wlatT) {
  __shared__ float tile[32][33];
  int l = blockIdx.z;
  const float* Wl = Wq + (size_t)l * 524288;
  int r0 = blockIdx.y * 32, c0 = blockIdx.x * 32;
  int tx = threadIdx.x & 31, ty = threadIdx.x >> 5;
#pragma unroll
  for (int i = 0; i < 4; ++i)
    tile[ty + i * 8][tx] = Wl[(size_t)(r0 + ty + i * 8) * 512 + c0 + tx];
  __syncthreads();
#pragma unroll
  for (int i = 0; i < 4; ++i) {
    int jl = ty + i * 8;
    int r = r0 + tx, c = c0 + jl;
    wlatT[(size_t)l * 1572864 + (size_t)c * 1024 + r] =
        f2bf(tile[tx][jl] * lnlg[l * 1024 + r] * 0.125f);
  }
}

__global__ __launch_bounds__(256) void k_fold_out(const float* __restrict__ Wout,
    ushort* __restrict__ woutT) {
  __shared__ float tile[32][33];
  int l = blockIdx.z;
  const float* Wl = Wout + (size_t)l * 524288;
  int r0 = blockIdx.y * 32, c0 = blockIdx.x * 32;
  int tx = threadIdx.x & 31, ty = threadIdx.x >> 5;
#pragma unroll
  for (int i = 0; i < 4; ++i)
    tile[ty + i * 8][tx] = Wl[(size_t)(r0 + ty + i * 8) * 1024 + c0 + tx];
  __syncthreads();
#pragma unroll
  for (int i = 0; i < 4; ++i) {
    int jl = ty + i * 8;
    woutT[(size_t)l * 524288 + (size_t)(c0 + jl) * 512 + r0 + tx] = f2bf(tile[tx][jl]);
  }
}

// ---------------------------------------------------------------------------
__global__ __launch_bounds__(256) void k_bias(const float* __restrict__ Wkv,
    const float* __restrict__ Wq, const float* __restrict__ lnmb,
    const float* __restrict__ lnlb, float* __restrict__ bkvm,
    float* __restrict__ blat) {
  __shared__ float red[4][64];
  int l = blockIdx.y;
  int c0 = blockIdx.x * 64;
  int tx = threadIdx.x & 63, dg = threadIdx.x >> 6;
  const float* Wsrc; const float* bv; int ld; float scale = 1.0f; float* outp;
  if (c0 < 1024) {
    Wsrc = Wkv + (size_t)l * 1048576 + c0 + tx; bv = lnmb + l * 1024; ld = 1024;
    outp = bkvm + l * 1024 + c0 + tx;
  } else if (c0 < 1536) {
    Wsrc = Wq + (size_t)l * 524288 + (c0 - 1024) + tx; bv = lnlb + l * 1024; ld = 512;
    outp = blat + l * 1536 + (c0 - 1024) + tx; scale = 0.125f;
  } else {
    Wsrc = Wkv + (size_t)l * 1048576 + (c0 - 1536) + tx; bv = lnlb + l * 1024; ld = 1024;
    outp = blat + l * 1536 + 512 + (c0 - 1536) + tx;
  }
  float acc = 0.f;
  for (int d = dg * 256; d < dg * 256 + 256; ++d)
    acc += bv[d] * Wsrc[(size_t)d * ld];
  red[dg][tx] = acc;
  __syncthreads();
  if (dg == 0) *outp = (red[0][tx] + red[1][tx] + red[2][tx] + red[3][tx]) * scale;
}

// ---------------------------------------------------------------------------
__global__ __launch_bounds__(256) void k_rownorm(const float* __restrict__ in,
    const float* __restrict__ pos, ushort* __restrict__ out) {
  int row = blockIdx.x, t = threadIdx.x;
  float4 v = *(const float4*)(in + (size_t)row * 1024 + t * 4);
  if (pos) {
    float4 p = *(const float4*)(pos + (size_t)(row & 511) * 1024 + t * 4);
    v.x += p.x; v.y += p.y; v.z += p.z; v.w += p.w;
  }
  float s = v.x + v.y + v.z + v.w;
  float q = v.x * v.x + v.y * v.y + v.z * v.z + v.w * v.w;
#pragma unroll
  for (int off = 32; off; off >>= 1) { s += __shfl_xor(s, off); q += __shfl_xor(q, off); }
  __shared__ float rs[4], rq[4];
  if ((t & 63) == 0) { rs[t >> 6] = s; rq[t >> 6] = q; }
  __syncthreads();
  s = rs[0] + rs[1] + rs[2] + rs[3];
  q = rq[0] + rq[1] + rq[2] + rq[3];
  float mean = s * (1.0f / 1024.0f);
  float var = q * (1.0f / 1024.0f) - mean * mean;
  float rstd = rsqrtf(var + 1e-5f);
  ushort4 o;
  o.x = f2bf((v.x - mean) * rstd);
  o.y = f2bf((v.y - mean) * rstd);
  o.z = f2bf((v.z - mean) * rstd);
  o.w = f2bf((v.w - mean) * rstd);
  *(ushort4*)(out + (size_t)row * 1024 + t * 4) = o;
}

__global__ __launch_bounds__(256) void k_finalln(const float* __restrict__ in,
    const float* __restrict__ g, const float* __restrict__ b, float* __restrict__ out) {
  int row = blockIdx.x, t = threadIdx.x;
  float4 v = *(const float4*)(in + (size_t)row * 1024 + t * 4);
  float s = v.x + v.y + v.z + v.w;
  float q = v.x * v.x + v.y * v.y + v.z * v.z + v.w * v.w;
#pragma unroll
  for (int off = 32; off; off >>= 1) { s += __shfl_xor(s, off); q += __shfl_xor(q, off); }
  __shared__ float rs[4], rq[4];
  if ((t & 63) == 0) { rs[t >> 6] = s; rq[t >> 6] = q; }
  __syncthreads();
  s = rs[0] + rs[1] + rs[2] + rs[3];
  q = rq[0] + rq[1] + rq[2] + rq[3];
  float mean = s * (1.0f / 1024.0f);
  float var = q * (1.0f / 1024.0f) - mean * mean;
  float rstd = rsqrtf(var + 1e-5f);
  float4 g4 = *(const float4*)(g + t * 4);
  float4 b4 = *(const float4*)(b + t * 4);
  float4 o;
  o.x = (v.x - mean) * rstd * g4.x + b4.x;
  o.y = (v.y - mean) * rstd * g4.y + b4.y;
  o.z = (v.z - mean) * rstd * g4.z + b4.z;
  o.w = (v.w - mean) * rstd * g4.w + b4.w;
  *(float4*)(out + (size_t)row * 1024 + t * 4) = o;
}

__global__ __launch_bounds__(256) void k_latinit(const float* __restrict__ latents,
                                                 float* __restrict__ lat) {
  int row = blockIdx.x, t = threadIdx.x;
  *(float4*)(lat + (size_t)row * 1024 + t * 4) =
      *(const float4*)(latents + (size_t)(row & 63) * 1024 + t * 4);
}

// ---------------------------------------------------------------------------
// 2-phase dbuf 64^2 GEMM. MODE 3: latent merged (q | K_lat | V_lat->Vt).
// MODE 2: f32 residual += (out-proj).
template <int MODE>
__global__ __launch_bounds__(256) void k_gemm64(const ushort* __restrict__ A,
    const ushort* __restrict__ Bt, const float* __restrict__ bias,
    ushort* __restrict__ o0, ushort* __restrict__ o1, ushort* __restrict__ o2,
    float* __restrict__ of, int N, int K) {
  __shared__ ushort Al[2][64][32];
  __shared__ ushort Bl[2][64][32];
  __shared__ ushort Cl[64][72];
  int tid = threadIdx.x, lane = tid & 63, w = tid >> 6;
  int wr = w >> 1, wc = w & 1;
  int m0 = blockIdx.y * 64, n0 = blockIdx.x * 64;
  f32x4 acc[2][2] = {};
  const ushort* Ag = A + (size_t)(m0 + w * 16 + (lane >> 2)) * K + (lane & 3) * 8;
  const ushort* Bg = Bt + (size_t)(n0 + w * 16 + (lane >> 2)) * K + (lane & 3) * 8;
  int fr = lane & 15, fk = (lane >> 4) << 3;
  int nt = K >> 5;
  gld16(&Al[0][w * 16][0], Ag);
  gld16(&Bl[0][w * 16][0], Bg);
  __syncthreads();
  for (int t = 0; t < nt; ++t) {
    int cur = t & 1;
    if (t + 1 < nt) {
      int k0 = (t + 1) << 5;
      gld16(&Al[cur ^ 1][w * 16][0], Ag + k0);
      gld16(&Bl[cur ^ 1][w * 16][0], Bg + k0);
    }
    short8_t a[2], b[2];
#pragma unroll
    for (int mt = 0; mt < 2; ++mt)
      a[mt] = *(const short8_t*)&Al[cur][wr * 32 + mt * 16 + fr][fk];
#pragma unroll
    for (int nt2 = 0; nt2 < 2; ++nt2)
      b[nt2] = *(const short8_t*)&Bl[cur][wc * 32 + nt2 * 16 + fr][fk];
#pragma unroll
    for (int mt = 0; mt < 2; ++mt)
#pragma unroll
      for (int nt2 = 0; nt2 < 2; ++nt2)
        acc[mt][nt2] = mfma16(a[mt], b[nt2], acc[mt][nt2]);
    __syncthreads();
  }
  if constexpr (MODE == 3) {
    if (n0 >= 1024) {
      // V_lat -> Vt via LDS transpose
#pragma unroll
      for (int mt = 0; mt < 2; ++mt)
#pragma unroll
        for (int nt2 = 0; nt2 < 2; ++nt2)
#pragma unroll
          for (int r = 0; r < 4; ++r) {
            int rl = wr * 32 + mt * 16 + ((lane >> 4) << 2) + r;
            int col = wc * 32 + nt2 * 16 + (lane & 15);
            Cl[rl][col] = f2bf(acc[mt][nt2][r] + bias[n0 + col]);
          }
      __syncthreads();
      int b_ = m0 >> 6;
#pragma unroll
      for (int q = 0; q < 2; ++q) {
        int task = tid + q * 256;
        int jg = task & 7, d = task >> 3;
        short8_t vv;
#pragma unroll
        for (int e = 0; e < 8; ++e) vv[e] = (short)Cl[jg * 8 + e][d];
        *(short8_t*)&o2[((size_t)(b_ * 512 + (n0 - 1024) + d)) * 576 + jg * 8] = vv;
      }
      return;
    }
  }
#pragma unroll
  for (int mt = 0; mt < 2; ++mt)
#pragma unroll
    for (int nt2 = 0; nt2 < 2; ++nt2)
#pragma unroll
      for (int r = 0; r < 4; ++r) {
        int row = m0 + wr * 32 + mt * 16 + ((lane >> 4) << 2) + r;
        int col = n0 + wc * 32 + nt2 * 16 + (lane & 15);
        float v = acc[mt][nt2][r] + (bias ? bias[col] : 0.0f);
        if constexpr (MODE == 3) {
          int b_ = row >> 6, ii = row & 63;
          if (col < 512) o0[(size_t)row * 512 + col] = f2bf(v);
          else           o1[(((size_t)(b_ * 576 + ii)) << 9) + (col - 512)] = f2bf(v);
        } else {
          of[(size_t)row * N + col] += v;
        }
      }
}

// ---------------------------------------------------------------------------
// Fused attention, zero staging: K from Kb rows, V from Vt rows.
__global__ __launch_bounds__(256) void k_attn(const ushort* __restrict__ Q,
    const ushort* __restrict__ Kb, const ushort* __restrict__ Vt,
    const int* __restrict__ amask, ushort* __restrict__ AO) {
  __shared__ ushort sim[32][584];
  int blk = blockIdx.x;
  int half = blk & 1, h = (blk >> 1) & 7, b = blk >> 4;
  int tid = threadIdx.x, lane = tid & 63, w = tid >> 6;
  int wr = w >> 1, wc = w & 1;
  short8_t aq0, aq1;
  {
    int qi = half * 32 + wr * 16 + (lane & 15);
    const ushort* qp = Q + ((size_t)(b * 64 + qi) << 9) + h * 64 + ((lane >> 4) << 3);
    aq0 = *(const short8_t*)qp;
    aq1 = *(const short8_t*)(qp + 32);
  }
  const ushort* kbase = Kb + (((size_t)(b * 576)) << 9) + h * 64 + ((lane >> 4) << 3);
  for (int jt = 0; jt < 9; ++jt) {
#pragma unroll
    for (int c2 = 0; c2 < 2; ++c2) {
      int ct = wc * 2 + c2;
      const ushort* kp = kbase + (((size_t)(jt * 64 + ct * 16 + (lane & 15))) << 9);
      short8_t bk0 = *(const short8_t*)kp;
      short8_t bk1 = *(const short8_t*)(kp + 32);
      f32x4 acc = {};
      acc = mfma16(aq0, bk0, acc);
      acc = mfma16(aq1, bk1, acc);
#pragma unroll
      for (int r = 0; r < 4; ++r)
        sim[wr * 16 + ((lane >> 4) << 2) + r][jt * 64 + ct * 16 + (lane & 15)] =
            f2bf(acc[r]);
    }
  }
  __syncthreads();
  unsigned mbits = 0;
#pragma unroll
  for (int c = 1; c < 9; ++c)
    if (amask[b * 512 + (c - 1) * 64 + lane]) mbits |= (1u << c);
  for (int rr = 0; rr < 8; ++rr) {
    int row = w * 8 + rr;
    float vals[9];
    float m = -3.0e38f;
#pragma unroll
    for (int c = 0; c < 9; ++c) {
      float v = bf2f(sim[row][c * 64 + lane]);
      vals[c] = v;
      if (!((mbits >> c) & 1)) m = fmaxf(m, v);
    }
#pragma unroll
    for (int off = 32; off; off >>= 1) m = fmaxf(m, __shfl_xor(m, off));
    float ssum = 0.f;
    float p[9];
#pragma unroll
    for (int c = 0; c < 9; ++c) {
      p[c] = ((mbits >> c) & 1) ? 0.f : __expf(vals[c] - m);
      ssum += p[c];
    }
#pragma unroll
    for (int off = 32; off; off >>= 1) ssum += __shfl_xor(ssum, off);
    float inv = 1.0f / ssum;
#pragma unroll
    for (int c = 0; c < 9; ++c)
      sim[row][c * 64 + lane] = f2bf(p[c] * inv);
  }
  __syncthreads();
  f32x4 oacc[2] = {};
  const ushort* vbase = Vt + ((size_t)(b * 512 + h * 64)) * 576 + ((lane >> 4) << 3);
  for (int jt = 0; jt < 9; ++jt) {
    short8_t pa0 = *(const short8_t*)&sim[wr * 16 + (lane & 15)][jt * 64 + ((lane >> 4) << 3)];
    short8_t pa1 = *(const short8_t*)&sim[wr * 16 + (lane & 15)][jt * 64 + 32 + ((lane >> 4) << 3)];
#pragma unroll
    for (int d2 = 0; d2 < 2; ++d2) {
      int dt = wc * 2 + d2;
      const ushort* vp = vbase + (size_t)(dt * 16 + (lane & 15)) * 576 + jt * 64;
      short8_t bv0 = *(const short8_t*)vp;
      short8_t bv1 = *(const short8_t*)(vp + 32);
      oacc[d2] = mfma16(pa0, bv0, oacc[d2]);
      oacc[d2] = mfma16(pa1, bv1, oacc[d2]);
    }
  }
#pragma unroll
  for (int d2 = 0; d2 < 2; ++d2) {
    int dt = wc * 2 + d2;
#pragma unroll
    for (int r = 0; r < 4; ++r) {
      int i = half * 32 + wr * 16 + ((lane >> 4) << 2) + r;
      int d = dt * 16 + (lane & 15);
      AO[((size_t)(b * 64 + i) << 9) + h * 64 + d] = f2bf(oacc[d2][r]);
    }
  }
}

// ---------------------------------------------------------------------------
extern "C" void kernel_launch(void* const* d_in, const int* in_sizes, int n_in,
                              void* d_out, int out_size, void* d_ws, size_t ws_size,
                              hipStream_t stream) {
  const float* x       = (const float*)d_in[0];
  const int*   amask   = (const int*)d_in[1];
  const float* latents = (const float*)d_in[2];
  const float* pos     = (const float*)d_in[3];
  const float* lnmg    = (const float*)d_in[4];
  const float* lnmb    = (const float*)d_in[5];
  const float* lnlg    = (const float*)d_in[6];
  const float* lnlb    = (const float*)d_in[7];
  const float* Wq      = (const float*)d_in[8];
  const float* Wkv     = (const float*)d_in[9];
  const float* Wout    = (const float*)d_in[10];
  const float* fg      = (const float*)d_in[11];
  const float* fb      = (const float*)d_in[12];
  float* out = (float*)d_out;
  char* ws = (char*)d_ws;

  ushort* xhat  = (ushort*)(ws + 0);           // [16384][1024] bf16   32 MiB
  ushort* wkvmT = (ushort*)(ws + 33554432);    // [6][1024][1024]      12 MiB
  ushort* wlatT = (ushort*)(ws + 46137344);    // [6][1536][1024]      18 MiB
  ushort* woutT = (ushort*)(ws + 65011712);    // [6][1024][512]        6 MiB
  float*  bkvm  = (float*)(ws + 71303168);     // [6][1024]
  float*  blat  = (float*)(ws + 71327744);     // [6][1536]
  float*  lat   = (float*)(ws + 71364608);     // [2048][1024] f32      8 MiB
  ushort* lhat  = (ushort*)(ws + 79753216);    // [2048][1024] bf16     4 MiB
  ushort* qbuf  = (ushort*)(ws + 83947520);    // [2048][512]  bf16     2 MiB
  ushort* Kbuf  = (ushort*)(ws + 86044672);    // [32][576][512]       18 MiB
  ushort* Vt    = (ushort*)(ws + 104919040);   // [32][512][576]       18 MiB
  ushort* aobuf = (ushort*)(ws + 123793408);   // [2048][512]           2 MiB

  // allow 160 KiB dynamic LDS for the media GEMM (idempotent; host-side only)
  (void)hipFuncSetAttribute((const void*)k_gemm256m,
                            hipFuncAttributeMaxDynamicSharedMemorySize, 163840);

  dim3 B256(256);
  k_fold_kv<<<dim3(32, 32, 6), B256, 0, stream>>>(Wkv, lnmg, lnlg, wkvmT, wlatT);
  k_fold_q<<<dim3(16, 32, 6), B256, 0, stream>>>(Wq, lnlg, wlatT);
  k_fold_out<<<dim3(32, 16, 6), B256, 0, stream>>>(Wout, woutT);
  k_bias<<<dim3(40, 6), B256, 0, stream>>>(Wkv, Wq, lnmb, lnlb, bkvm, blat);
  k_rownorm<<<16384, B256, 0, stream>>>(x, pos, xhat);
  k_latinit<<<2048, B256, 0, stream>>>(latents, lat);

  for (int l = 0; l < 6; ++l) {
    k_rownorm<<<2048, B256, 0, stream>>>(lat, nullptr, lhat);
    // merged latent GEMM: [q | K_lat | V_lat], N=1536
    k_gemm64<3><<<dim3(24, 32), B256, 0, stream>>>(
        lhat, wlatT + (size_t)l * 1572864, blat + l * 1536,
        qbuf, Kbuf, Vt, nullptr, 1536, 1024);
    // media KV: 256^2 pipelined, 256 blocks x 512 thr, 160 KiB dynamic LDS
    k_gemm256m<<<dim3(256), dim3(512), 163840, stream>>>(
        xhat, wkvmT + (size_t)l * 1048576, bkvm + l * 1024, Kbuf, Vt);
    k_attn<<<512, B256, 0, stream>>>(qbuf, Kbuf, Vt, amask, aobuf);
    // lat += attn_out @ Wout
    k_gemm64<2><<<dim3(16, 32), B256, 0, stream>>>(
        aobuf, woutT + (size_t)l * 524288, nullptr,
        nullptr, nullptr, nullptr, lat, 1024, 512);
  }
  k_finalln<<<2048, B256, 0, stream>>>(lat, fg, fb, out);
}